// Round 2
// baseline (575.263 us; speedup 1.0000x reference)
//
#include <hip/hip_runtime.h>
#include <math.h>

#define H 12
#define S 1024
#define D 128
#define NROWS (H * S) // 12288

typedef __attribute__((ext_vector_type(8))) _Float16 f16x8; // 8 fp16 in 4 VGPRs
typedef __attribute__((ext_vector_type(4))) float f32x4;
typedef __attribute__((ext_vector_type(4))) int i32x4;

__device__ __forceinline__ short f2h(float f) { // RNE float->fp16, bits as short
    _Float16 h = (_Float16)f;
    return __builtin_bit_cast(short, h);
}
__device__ __forceinline__ float h2f(short s) {
    return (float)__builtin_bit_cast(_Float16, s);
}
__device__ __forceinline__ f16x8 fneg8(f16x8 v) { // packed sign flip
    i32x4 u = __builtin_bit_cast(i32x4, v);
    u ^= (int)0x80008000;
    return __builtin_bit_cast(f16x8, u);
}

// ---- workspace layout (BYTE offsets) ----
// qp fp16 [12288][256] r/i ; kp fp16 [12288][128] r/i ; vpT fp16 [H][128][1024] r/i
// gp fp16 [12288][128] r/i ; acat fp16 [12288][256] r/i ; lam
#define WS_QP_R   0ULL
#define WS_QP_I   6291456ULL
#define WS_KP_R   12582912ULL
#define WS_KP_I   15728640ULL
#define WS_VPT_R  18874368ULL
#define WS_VPT_I  22020096ULL
#define WS_GP_R   25165824ULL
#define WS_GP_I   28311552ULL
#define WS_ACAT_R 31457280ULL
#define WS_ACAT_I 37748736ULL
#define WS_LAM    44040192ULL

// ============================================================
__global__ void lam_kernel(const float* __restrict__ lq1, const float* __restrict__ lk1,
                           const float* __restrict__ lq2, const float* __restrict__ lk2,
                           float* __restrict__ lam_out)
{
    int t = threadIdx.x; // 128 threads
    float p1 = lq1[t] * lk1[t];
    float p2 = lq2[t] * lk2[t];
    #pragma unroll
    for (int off = 32; off; off >>= 1) {
        p1 += __shfl_xor(p1, off);
        p2 += __shfl_xor(p2, off);
    }
    __shared__ float s1[2], s2[2];
    if ((t & 63) == 0) { s1[t >> 6] = p1; s2[t >> 6] = p2; }
    __syncthreads();
    if (t == 0) {
        float l1 = expf(s1[0] + s1[1]);
        float l2 = expf(s2[0] + s2[1]);
        float x = l1 - l2 + 0.3555090675909693f; // 0.8 - 0.6*exp(-0.3)
        lam_out[0] = 1.0f / (1.0f + expf(-x));
    }
}

// ============================================================
// ALL FOUR projections in ONE dispatch. grid = (192, 10), 64x64 tiles:
//  y 0-3: q-proj  (M=256, fp16 out, +pe_q)       col0 = y*64
//  y 4-5: k-proj  (M=128, fp16 out, +pe_k)       col0 = (y-4)*64
//  y 6-7: v-proj  (M=128, fp16 transposed out)   col0 = (y-6)*64
//  y 8-9: g-proj  (M=128, fp16 out)              col0 = (y-8)*64
// ============================================================
__global__ __launch_bounds__(256) void proj_all(
    const float* __restrict__ q_r, const float* __restrict__ q_i,
    const float* __restrict__ k_r, const float* __restrict__ k_i,
    const float* __restrict__ v_r, const float* __restrict__ v_i,
    const float* __restrict__ pe_q_r, const float* __restrict__ pe_q_i,
    const float* __restrict__ pe_k_r, const float* __restrict__ pe_k_i,
    const float* __restrict__ qw_r, const float* __restrict__ qw_i,
    const float* __restrict__ qb_r, const float* __restrict__ qb_i,
    const float* __restrict__ kw_r, const float* __restrict__ kw_i,
    const float* __restrict__ kb_r, const float* __restrict__ kb_i,
    const float* __restrict__ vw_r, const float* __restrict__ vw_i,
    const float* __restrict__ vb_r, const float* __restrict__ vb_i,
    const float* __restrict__ gw_r, const float* __restrict__ gw_i,
    const float* __restrict__ gb_r, const float* __restrict__ gb_i,
    short* __restrict__ qp_r, short* __restrict__ qp_i,
    short* __restrict__ kp_r, short* __restrict__ kp_i,
    short* __restrict__ vpT_r, short* __restrict__ vpT_i,
    short* __restrict__ gp_r, short* __restrict__ gp_i)
{
    const int y = blockIdx.y;
    const float *xr, *xi, *wr, *wi, *br, *bi, *per = nullptr, *pei = nullptr;
    short *outr_, *outi_;
    int M, omode, col0;
    if (y < 4)      { xr = q_r; xi = q_i; wr = qw_r; wi = qw_i; br = qb_r; bi = qb_i;
                      per = pe_q_r; pei = pe_q_i; outr_ = qp_r; outi_ = qp_i;
                      M = 256; omode = 1; col0 = y * 64; }
    else if (y < 6) { xr = k_r; xi = k_i; wr = kw_r; wi = kw_i; br = kb_r; bi = kb_i;
                      per = pe_k_r; pei = pe_k_i; outr_ = kp_r; outi_ = kp_i;
                      M = 128; omode = 1; col0 = (y - 4) * 64; }
    else if (y < 8) { xr = v_r; xi = v_i; wr = vw_r; wi = vw_i; br = vb_r; bi = vb_i;
                      outr_ = vpT_r; outi_ = vpT_i;
                      M = 128; omode = 2; col0 = (y - 6) * 64; }
    else            { xr = q_r; xi = q_i; wr = gw_r; wi = gw_i; br = gb_r; bi = gb_i;
                      outr_ = gp_r; outi_ = gp_i;
                      M = 128; omode = 1; col0 = (y - 8) * 64; }

    __shared__ short As[64 * 72], Brs[64 * 72], Bis[64 * 72];
    const int t = threadIdx.x;
    const int row0 = blockIdx.x * 64;
    const int lane = t & 63, wid = t >> 6;
    const int wm = (wid >> 1) * 32, wn = (wid & 1) * 32;
    const int fm = lane & 15, fq = lane >> 4;
    f32x4 zero4 = {0.f, 0.f, 0.f, 0.f};
    f32x4 accr[2][2], acci[2][2];
    #pragma unroll
    for (int i = 0; i < 2; ++i)
        #pragma unroll
        for (int j = 0; j < 2; ++j) { accr[i][j] = zero4; acci[i][j] = zero4; }

    for (int c = 0; c < 4; ++c) {
        const bool hi = (c >= 2);
        const int kb = (c & 1) * 64;
        const float* Asrc = hi ? xi : xr;
        const float* Brsrc = hi ? wi : wr;
        const float* Bisrc = hi ? wr : wi;
        const float bsign = hi ? -1.0f : 1.0f;
        __syncthreads();
        #pragma unroll
        for (int it = 0; it < 4; ++it) {
            int lin = it * 256 + t;
            int r = lin >> 4, k4 = (lin & 15) * 4;
            float4 va = *(const float4*)&Asrc[(size_t)(row0 + r) * 128 + kb + k4];
            *(short4*)&As[r * 72 + k4] = make_short4(f2h(va.x), f2h(va.y), f2h(va.z), f2h(va.w));
            float4 vr = *(const float4*)&Brsrc[(size_t)(col0 + r) * 128 + kb + k4];
            *(short4*)&Brs[r * 72 + k4] = make_short4(f2h(bsign * vr.x), f2h(bsign * vr.y),
                                                      f2h(bsign * vr.z), f2h(bsign * vr.w));
            float4 vi = *(const float4*)&Bisrc[(size_t)(col0 + r) * 128 + kb + k4];
            *(short4*)&Bis[r * 72 + k4] = make_short4(f2h(vi.x), f2h(vi.y), f2h(vi.z), f2h(vi.w));
        }
        __syncthreads();
        #pragma unroll
        for (int ks = 0; ks < 64; ks += 32) {
            f16x8 bfr[2], bfi[2];
            #pragma unroll
            for (int j = 0; j < 2; ++j) {
                bfr[j] = *(const f16x8*)&Brs[(wn + j * 16 + fm) * 72 + ks + fq * 8];
                bfi[j] = *(const f16x8*)&Bis[(wn + j * 16 + fm) * 72 + ks + fq * 8];
            }
            #pragma unroll
            for (int i = 0; i < 2; ++i) {
                f16x8 a = *(const f16x8*)&As[(wm + i * 16 + fm) * 72 + ks + fq * 8];
                #pragma unroll
                for (int j = 0; j < 2; ++j) {
                    accr[i][j] = __builtin_amdgcn_mfma_f32_16x16x32_f16(a, bfr[j], accr[i][j], 0, 0, 0);
                    acci[i][j] = __builtin_amdgcn_mfma_f32_16x16x32_f16(a, bfi[j], acci[i][j], 0, 0, 0);
                }
            }
        }
    }
    #pragma unroll
    for (int i = 0; i < 2; ++i)
        #pragma unroll
        for (int j = 0; j < 2; ++j) {
            int colc = col0 + wn + j * 16 + fm;
            float bbr = br[colc], bbi = bi[colc];
            if (omode == 2) {
                int rb = row0 + wm + i * 16 + fq * 4;
                int hq = rb >> 10, sq = rb & 1023;
                short4 o_r4 = make_short4(f2h(accr[i][j][0] + bbr), f2h(accr[i][j][1] + bbr),
                                          f2h(accr[i][j][2] + bbr), f2h(accr[i][j][3] + bbr));
                short4 o_i4 = make_short4(f2h(acci[i][j][0] + bbi), f2h(acci[i][j][1] + bbi),
                                          f2h(acci[i][j][2] + bbi), f2h(acci[i][j][3] + bbi));
                size_t ob = ((size_t)(hq * 128 + colc)) * 1024 + sq;
                *(short4*)&outr_[ob] = o_r4;
                *(short4*)&outi_[ob] = o_i4;
            } else {
                #pragma unroll
                for (int reg = 0; reg < 4; ++reg) {
                    int rr = row0 + wm + i * 16 + fq * 4 + reg;
                    float o_r = accr[i][j][reg] + bbr;
                    float o_i = acci[i][j][reg] + bbi;
                    if (per) {
                        o_r += per[(size_t)rr * 128 + (colc & 127)];
                        o_i += pei[(size_t)rr * 128 + (colc & 127)];
                    }
                    outr_[(size_t)rr * M + colc] = f2h(o_r);
                    outi_[(size_t)rr * M + colc] = f2h(o_i);
                }
            }
        }
}

// ============================================================
// o-projection: fp16 gated input gp, fp32 weights, fp32 out. 64x64 tiles.
// ============================================================
__global__ __launch_bounds__(256) void oproj_mfma(
    const short* __restrict__ gp_r, const short* __restrict__ gp_i,
    const float* __restrict__ wr, const float* __restrict__ wi,
    const float* __restrict__ br, const float* __restrict__ bi,
    float* __restrict__ outr, float* __restrict__ outi)
{
    __shared__ short As[64 * 72], Brs[64 * 72], Bis[64 * 72];
    const int t = threadIdx.x;
    const int row0 = blockIdx.x * 64, col0 = blockIdx.y * 64;
    const int lane = t & 63, wid = t >> 6;
    const int wm = (wid >> 1) * 32, wn = (wid & 1) * 32;
    const int fm = lane & 15, fq = lane >> 4;
    f32x4 zero4 = {0.f, 0.f, 0.f, 0.f};
    f32x4 accr[2][2], acci[2][2];
    #pragma unroll
    for (int i = 0; i < 2; ++i)
        #pragma unroll
        for (int j = 0; j < 2; ++j) { accr[i][j] = zero4; acci[i][j] = zero4; }

    for (int c = 0; c < 4; ++c) {
        const bool hi = (c >= 2);
        const int kb = (c & 1) * 64;
        const short* Asrc = hi ? gp_i : gp_r;
        const float* Brsrc = hi ? wi : wr;
        const float* Bisrc = hi ? wr : wi;
        const float bsign = hi ? -1.0f : 1.0f;
        __syncthreads();
        #pragma unroll
        for (int it = 0; it < 4; ++it) {
            int lin = it * 256 + t;
            int r = lin >> 4, k4 = (lin & 15) * 4;
            *(short4*)&As[r * 72 + k4] = *(const short4*)&Asrc[(size_t)(row0 + r) * 128 + kb + k4];
            float4 vr = *(const float4*)&Brsrc[(size_t)(col0 + r) * 128 + kb + k4];
            *(short4*)&Brs[r * 72 + k4] = make_short4(f2h(bsign * vr.x), f2h(bsign * vr.y),
                                                      f2h(bsign * vr.z), f2h(bsign * vr.w));
            float4 vi = *(const float4*)&Bisrc[(size_t)(col0 + r) * 128 + kb + k4];
            *(short4*)&Bis[r * 72 + k4] = make_short4(f2h(vi.x), f2h(vi.y), f2h(vi.z), f2h(vi.w));
        }
        __syncthreads();
        #pragma unroll
        for (int ks = 0; ks < 64; ks += 32) {
            f16x8 bfr[2], bfi[2];
            #pragma unroll
            for (int j = 0; j < 2; ++j) {
                bfr[j] = *(const f16x8*)&Brs[(wn + j * 16 + fm) * 72 + ks + fq * 8];
                bfi[j] = *(const f16x8*)&Bis[(wn + j * 16 + fm) * 72 + ks + fq * 8];
            }
            #pragma unroll
            for (int i = 0; i < 2; ++i) {
                f16x8 a = *(const f16x8*)&As[(wm + i * 16 + fm) * 72 + ks + fq * 8];
                #pragma unroll
                for (int j = 0; j < 2; ++j) {
                    accr[i][j] = __builtin_amdgcn_mfma_f32_16x16x32_f16(a, bfr[j], accr[i][j], 0, 0, 0);
                    acci[i][j] = __builtin_amdgcn_mfma_f32_16x16x32_f16(a, bfi[j], acci[i][j], 0, 0, 0);
                }
            }
        }
    }
    #pragma unroll
    for (int i = 0; i < 2; ++i)
        #pragma unroll
        for (int j = 0; j < 2; ++j) {
            int colc = col0 + wn + j * 16 + fm;
            float bbr = br[colc], bbi = bi[colc];
            #pragma unroll
            for (int reg = 0; reg < 4; ++reg) {
                int rr = row0 + wm + i * 16 + fq * 4 + reg;
                outr[(size_t)rr * 128 + colc] = accr[i][j][reg] + bbr;
                outi[(size_t)rr * 128 + colc] = acci[i][j][reg] + bbi;
            }
        }
}

// ============================================================
// FUSED flash-style attention: one block = (head h, map, 32 q-rows).
// 2 waves/block, each wave owns 16 q-rows. Loop k-chunks of 64:
//   stage K(r,i) -> QK^T complex MFMA (Q frags in regs) -> mag ->
//   online softmax (running m,l; O-rescale) -> P to LDS (fp16) ->
//   stage V(r,i) into K's LDS space (K dead) -> P@V MFMA into accO.
// No S*S materialization: kills the 150MB w16 round-trip + smstats.
// Frag patterns identical to proven score_mfma / av_mfma.
// LDS: KV union 36.9KB + P 4.6KB = 41.5KB -> 3 blocks/CU; grid 768 = 3/CU.
// ============================================================
#define KI_OFF 8704   // shorts: Ki base in KV (Kr is 64*136)
#define VI_OFF 9216   // shorts: Vi base in KV (Vr is 128*72)
__global__ __launch_bounds__(128) void fused_attn(
    const short* __restrict__ qp_r, const short* __restrict__ qp_i,
    const short* __restrict__ kp_r, const short* __restrict__ kp_i,
    const short* __restrict__ vpT_r, const short* __restrict__ vpT_i,
    short* __restrict__ acat_r, short* __restrict__ acat_i)
{
    __shared__ __align__(16) short KV[18432]; // max(K: 2*64*136, V: 2*128*72)
    __shared__ __align__(16) short Pl[32 * 72];
    const int t = threadIdx.x;
    const int lane = t & 63, wid = t >> 6;      // wid 0..1
    const int fm = lane & 15, fq = lane >> 4;   // fq 0..3
    const int q0 = blockIdx.x * 32;
    const int map = blockIdx.y;
    const int h = blockIdx.z;

    // Q fragments in registers: wave's 16 q-rows, K-dim 128 (this map's half)
    f16x8 qR[4], qI[4];
    {
        size_t qrow = (size_t)(h * S + q0 + wid * 16 + fm) * 256 + map * 128;
        #pragma unroll
        for (int ks = 0; ks < 4; ++ks) {
            qR[ks] = *(const f16x8*)&qp_r[qrow + ks * 32 + fq * 8];
            qI[ks] = *(const f16x8*)&qp_i[qrow + ks * 32 + fq * 8];
        }
    }
    f32x4 zero4 = {0.f, 0.f, 0.f, 0.f};
    f32x4 accO[2][8]; // [comp r/i][d-frag]; C rows = q (fq*4+reg), cols = d (fm)
    #pragma unroll
    for (int c = 0; c < 2; ++c)
        #pragma unroll
        for (int dj = 0; dj < 8; ++dj) accO[c][dj] = zero4;
    float m_run[4], l_run[4];
    #pragma unroll
    for (int reg = 0; reg < 4; ++reg) { m_run[reg] = -3.0e38f; l_run[reg] = 0.f; }

    const float scale = 0.08838834764831845f;

    for (int k0 = 0; k0 < S; k0 += 64) {
        __syncthreads(); // prev PV done: KV free for K
        // ---- stage K chunk: Kr/Ki [64 krows][136], 128 d cols ----
        #pragma unroll
        for (int it = 0; it < 8; ++it) {
            int lin = it * 128 + t;
            int r = lin >> 4, c8 = (lin & 15) * 8;
            size_t src = (size_t)(h * S + k0 + r) * 128 + c8;
            *(i32x4*)&KV[r * 136 + c8]          = *(const i32x4*)&kp_r[src];
            *(i32x4*)&KV[KI_OFF + r * 136 + c8] = *(const i32x4*)&kp_i[src];
        }
        __syncthreads();
        // ---- S tile: wave's 16 q-rows x 64 k-cols, complex QK^T ----
        // s_r = qr.kr + qi.ki ; s_i = qi.kr - qr.ki  (proven score_mfma phases)
        f32x4 sr[4], si[4];
        #pragma unroll
        for (int j = 0; j < 4; ++j) { sr[j] = zero4; si[j] = zero4; }
        #pragma unroll
        for (int ks = 0; ks < 4; ++ks) {
            f16x8 aR = qR[ks], aI = qI[ks], nR = fneg8(qR[ks]);
            #pragma unroll
            for (int j = 0; j < 4; ++j) {
                int bo = (j * 16 + fm) * 136 + ks * 32 + fq * 8;
                f16x8 bR = *(const f16x8*)&KV[bo];
                f16x8 bI = *(const f16x8*)&KV[KI_OFF + bo];
                sr[j] = __builtin_amdgcn_mfma_f32_16x16x32_f16(aR, bR, sr[j], 0, 0, 0);
                si[j] = __builtin_amdgcn_mfma_f32_16x16x32_f16(aI, bR, si[j], 0, 0, 0);
                sr[j] = __builtin_amdgcn_mfma_f32_16x16x32_f16(aI, bI, sr[j], 0, 0, 0);
                si[j] = __builtin_amdgcn_mfma_f32_16x16x32_f16(nR, bI, si[j], 0, 0, 0);
            }
        }
        // ---- mag + online softmax (rows owned exclusively by this wave) ----
        float p[4][4]; // [j][reg]
        #pragma unroll
        for (int j = 0; j < 4; ++j)
            #pragma unroll
            for (int reg = 0; reg < 4; ++reg)
                p[j][reg] = sqrtf(fmaf(sr[j][reg], sr[j][reg],
                                       fmaf(si[j][reg], si[j][reg], 1e-8f))) * scale;
        float sc[4];
        #pragma unroll
        for (int reg = 0; reg < 4; ++reg) {
            float mx = fmaxf(fmaxf(p[0][reg], p[1][reg]), fmaxf(p[2][reg], p[3][reg]));
            #pragma unroll
            for (int off = 1; off < 16; off <<= 1) mx = fmaxf(mx, __shfl_xor(mx, off));
            float mnew = fmaxf(m_run[reg], mx);
            sc[reg] = __expf(m_run[reg] - mnew);
            m_run[reg] = mnew;
            float ssum = 0.f;
            #pragma unroll
            for (int j = 0; j < 4; ++j) {
                p[j][reg] = __expf(p[j][reg] - mnew);
                ssum += p[j][reg];
            }
            #pragma unroll
            for (int off = 1; off < 16; off <<= 1) ssum += __shfl_xor(ssum, off);
            l_run[reg] = l_run[reg] * sc[reg] + ssum;
        }
        // rescale accumulated O
        #pragma unroll
        for (int c = 0; c < 2; ++c)
            #pragma unroll
            for (int dj = 0; dj < 8; ++dj)
                #pragma unroll
                for (int reg = 0; reg < 4; ++reg)
                    accO[c][dj][reg] *= sc[reg];
        __syncthreads(); // all waves done reading K: KV free for V
        // ---- stage V chunk into KV: Vr/Vi [128 d][72], 64 k cols ----
        #pragma unroll
        for (int it = 0; it < 8; ++it) {
            int lin = it * 128 + t;
            int dd = lin >> 3, c8 = (lin & 7) * 8;
            size_t src = (size_t)(h * 128 + dd) * 1024 + k0 + c8;
            *(i32x4*)&KV[dd * 72 + c8]          = *(const i32x4*)&vpT_r[src];
            *(i32x4*)&KV[VI_OFF + dd * 72 + c8] = *(const i32x4*)&vpT_i[src];
        }
        // ---- write P (fp16) to LDS, row-major [q][k] like av's W ----
        #pragma unroll
        for (int j = 0; j < 4; ++j)
            #pragma unroll
            for (int reg = 0; reg < 4; ++reg)
                Pl[(wid * 16 + fq * 4 + reg) * 72 + j * 16 + fm] = f2h(p[j][reg]);
        __syncthreads();
        // ---- PV: accO[comp][dj] += P . V  (proven av_mfma pattern) ----
        #pragma unroll
        for (int ks2 = 0; ks2 < 2; ++ks2) {
            f16x8 w8 = *(const f16x8*)&Pl[(wid * 16 + fm) * 72 + ks2 * 32 + fq * 8];
            #pragma unroll
            for (int dj = 0; dj < 8; ++dj) {
                int vo = (dj * 16 + fm) * 72 + ks2 * 32 + fq * 8;
                f16x8 br = *(const f16x8*)&KV[vo];
                f16x8 bi = *(const f16x8*)&KV[VI_OFF + vo];
                accO[0][dj] = __builtin_amdgcn_mfma_f32_16x16x32_f16(w8, br, accO[0][dj], 0, 0, 0);
                accO[1][dj] = __builtin_amdgcn_mfma_f32_16x16x32_f16(w8, bi, accO[1][dj], 0, 0, 0);
            }
        }
    }
    // ---- epilogue: O / l -> acat (cols map*128 .. +128) ----
    #pragma unroll
    for (int reg = 0; reg < 4; ++reg) {
        float invl = 1.0f / l_run[reg];
        int q = q0 + wid * 16 + fq * 4 + reg;
        size_t rowb = (size_t)(h * S + q) * 256 + map * 128;
        #pragma unroll
        for (int dj = 0; dj < 8; ++dj) {
            int d = dj * 16 + fm;
            acat_r[rowb + d] = f2h(accO[0][dj][reg] * invl);
            acat_i[rowb + d] = f2h(accO[1][dj][reg] * invl);
        }
    }
}

// ============================================================
// RMS over 256 complex + sub_w + (a1 - lam*a2) + complex gate.
// acat fp16 in, gp fp16 in/out (in place).
// ============================================================
__global__ __launch_bounds__(256) void rmsgate_kernel(
    const short* __restrict__ acat_r, const short* __restrict__ acat_i,
    const float* __restrict__ sub_w, const float* __restrict__ lam_ptr,
    short* __restrict__ gp_r, short* __restrict__ gp_i)
{
    int row = blockIdx.x;
    int t = threadIdx.x;
    float ar = h2f(acat_r[(size_t)row * 256 + t]);
    float ai = h2f(acat_i[(size_t)row * 256 + t]);
    float ss = fmaf(ar, ar, ai * ai);
    #pragma unroll
    for (int off = 32; off; off >>= 1) ss += __shfl_xor(ss, off);
    __shared__ float red[4];
    if ((t & 63) == 0) red[t >> 6] = ss;
    __syncthreads();
    float total = red[0] + red[1] + red[2] + red[3];
    float inv_rms = 1.0f / sqrtf(total * (1.0f / 256.0f) + 1e-5f);
    float sw = sub_w[t];
    __shared__ float Cr[256], Ci[256];
    Cr[t] = ar * inv_rms * sw;
    Ci[t] = ai * inv_rms * sw;
    __syncthreads();
    if (t < 128) {
        float lam = lam_ptr[0];
        float o_r = Cr[t] - lam * Cr[t + 128];
        float o_i = Ci[t] - lam * Ci[t + 128];
        float gr = h2f(gp_r[(size_t)row * 128 + t]);
        float gi = h2f(gp_i[(size_t)row * 128 + t]);
        gp_r[(size_t)row * 128 + t] = f2h(gr * o_r - gi * o_i);
        gp_i[(size_t)row * 128 + t] = f2h(gr * o_i + gi * o_r);
    }
}

// ============================================================
extern "C" void kernel_launch(void* const* d_in, const int* in_sizes, int n_in,
                              void* d_out, int out_size, void* d_ws, size_t ws_size,
                              hipStream_t stream)
{
    (void)in_sizes; (void)n_in; (void)out_size; (void)ws_size;
    const float* q_r    = (const float*)d_in[0];
    const float* q_i    = (const float*)d_in[1];
    const float* k_r    = (const float*)d_in[2];
    const float* k_i    = (const float*)d_in[3];
    const float* v_r    = (const float*)d_in[4];
    const float* v_i    = (const float*)d_in[5];
    const float* pe_q_r = (const float*)d_in[6];
    const float* pe_q_i = (const float*)d_in[7];
    const float* pe_k_r = (const float*)d_in[8];
    const float* pe_k_i = (const float*)d_in[9];
    const float* qw_r   = (const float*)d_in[10];
    const float* qw_i   = (const float*)d_in[11];
    const float* qb_r   = (const float*)d_in[12];
    const float* qb_i   = (const float*)d_in[13];
    const float* kw_r   = (const float*)d_in[14];
    const float* kw_i   = (const float*)d_in[15];
    const float* kb_r   = (const float*)d_in[16];
    const float* kb_i   = (const float*)d_in[17];
    const float* vw_r   = (const float*)d_in[18];
    const float* vw_i   = (const float*)d_in[19];
    const float* vb_r   = (const float*)d_in[20];
    const float* vb_i   = (const float*)d_in[21];
    const float* gw_r   = (const float*)d_in[22];
    const float* gw_i   = (const float*)d_in[23];
    const float* gb_r   = (const float*)d_in[24];
    const float* gb_i   = (const float*)d_in[25];
    const float* ow_r   = (const float*)d_in[26];
    const float* ow_i   = (const float*)d_in[27];
    const float* ob_r   = (const float*)d_in[28];
    const float* ob_i   = (const float*)d_in[29];
    const float* lq1    = (const float*)d_in[30];
    const float* lk1    = (const float*)d_in[31];
    const float* lq2    = (const float*)d_in[32];
    const float* lk2    = (const float*)d_in[33];
    const float* sub_w  = (const float*)d_in[34];

    char* ws = (char*)d_ws;
    short* qp_r   = (short*)(ws + WS_QP_R);
    short* qp_i   = (short*)(ws + WS_QP_I);
    short* kp_r   = (short*)(ws + WS_KP_R);
    short* kp_i   = (short*)(ws + WS_KP_I);
    short* vpT_r  = (short*)(ws + WS_VPT_R);
    short* vpT_i  = (short*)(ws + WS_VPT_I);
    short* gp_r   = (short*)(ws + WS_GP_R);
    short* gp_i   = (short*)(ws + WS_GP_I);
    short* acat_r = (short*)(ws + WS_ACAT_R);
    short* acat_i = (short*)(ws + WS_ACAT_I);
    float* lam    = (float*)(ws + WS_LAM);

    float* out_r = (float*)d_out;
    float* out_i = out_r + (size_t)NROWS * D;

    lam_kernel<<<1, 128, 0, stream>>>(lq1, lk1, lq2, lk2, lam);

    // ALL projections in one dispatch (q/k -> fp16 +PE; v -> fp16 T; g -> fp16)
    proj_all<<<dim3(192, 10), 256, 0, stream>>>(
        q_r, q_i, k_r, k_i, v_r, v_i, pe_q_r, pe_q_i, pe_k_r, pe_k_i,
        qw_r, qw_i, qb_r, qb_i, kw_r, kw_i, kb_r, kb_i,
        vw_r, vw_i, vb_r, vb_i, gw_r, gw_i, gb_r, gb_i,
        qp_r, qp_i, kp_r, kp_i, vpT_r, vpT_i, gp_r, gp_i);

    // flash-style fused scores+softmax+AV: no S*S materialization
    fused_attn<<<dim3(32, 2, H), 128, 0, stream>>>(
        qp_r, qp_i, kp_r, kp_i, vpT_r, vpT_i, acat_r, acat_i);

    rmsgate_kernel<<<NROWS, 256, 0, stream>>>(acat_r, acat_i, sub_w, lam, gp_r, gp_i);

    oproj_mfma<<<dim3(192, 2), 256, 0, stream>>>(gp_r, gp_i, ow_r, ow_i, ob_r, ob_i, out_r, out_i);
}

// Round 3
// 345.837 us; speedup vs baseline: 1.6634x; 1.6634x over previous
//
#include <hip/hip_runtime.h>
#include <math.h>

#define H 12
#define S 1024
#define D 128
#define NROWS (H * S) // 12288

typedef __attribute__((ext_vector_type(8))) _Float16 f16x8; // 8 fp16 in 4 VGPRs
typedef __attribute__((ext_vector_type(4))) float f32x4;
typedef __attribute__((ext_vector_type(4))) int i32x4;

__device__ __forceinline__ short f2h(float f) { // RNE float->fp16, bits as short
    _Float16 h = (_Float16)f;
    return __builtin_bit_cast(short, h);
}
__device__ __forceinline__ float h2f(short s) {
    return (float)__builtin_bit_cast(_Float16, s);
}
__device__ __forceinline__ f16x8 fneg8(f16x8 v) { // packed sign flip
    i32x4 u = __builtin_bit_cast(i32x4, v);
    u ^= (int)0x80008000;
    return __builtin_bit_cast(f16x8, u);
}

// ---- workspace layout (BYTE offsets) ----
// qp fp16 [12288][256] r/i ; kp fp16 [12288][128] r/i ; vpT fp16 [H][128][1024] r/i
// gp fp16 [12288][128] r/i ; acat fp16 [12288][256] r/i ; lam ;
// w16 fp16 per chunk-head 2*S*S
#define WS_QP_R   0ULL
#define WS_QP_I   6291456ULL
#define WS_KP_R   12582912ULL
#define WS_KP_I   15728640ULL
#define WS_VPT_R  18874368ULL
#define WS_VPT_I  22020096ULL
#define WS_GP_R   25165824ULL
#define WS_GP_I   28311552ULL
#define WS_ACAT_R 31457280ULL
#define WS_ACAT_I 37748736ULL
#define WS_LAM    44040192ULL
#define WS_SC     44040448ULL
#define W16_PER_HEAD   4194304ULL // 2*1024*1024*2B

// ============================================================
__global__ void lam_kernel(const float* __restrict__ lq1, const float* __restrict__ lk1,
                           const float* __restrict__ lq2, const float* __restrict__ lk2,
                           float* __restrict__ lam_out)
{
    int t = threadIdx.x; // 128 threads
    float p1 = lq1[t] * lk1[t];
    float p2 = lq2[t] * lk2[t];
    #pragma unroll
    for (int off = 32; off; off >>= 1) {
        p1 += __shfl_xor(p1, off);
        p2 += __shfl_xor(p2, off);
    }
    __shared__ float s1[2], s2[2];
    if ((t & 63) == 0) { s1[t >> 6] = p1; s2[t >> 6] = p2; }
    __syncthreads();
    if (t == 0) {
        float l1 = expf(s1[0] + s1[1]);
        float l2 = expf(s2[0] + s2[1]);
        float x = l1 - l2 + 0.3555090675909693f; // 0.8 - 0.6*exp(-0.3)
        lam_out[0] = 1.0f / (1.0f + expf(-x));
    }
}

// ============================================================
// ALL FOUR projections in ONE dispatch. grid = (192, 10), 64x64 tiles.
// (unchanged — proven r1 kernel)
// ============================================================
__global__ __launch_bounds__(256) void proj_all(
    const float* __restrict__ q_r, const float* __restrict__ q_i,
    const float* __restrict__ k_r, const float* __restrict__ k_i,
    const float* __restrict__ v_r, const float* __restrict__ v_i,
    const float* __restrict__ pe_q_r, const float* __restrict__ pe_q_i,
    const float* __restrict__ pe_k_r, const float* __restrict__ pe_k_i,
    const float* __restrict__ qw_r, const float* __restrict__ qw_i,
    const float* __restrict__ qb_r, const float* __restrict__ qb_i,
    const float* __restrict__ kw_r, const float* __restrict__ kw_i,
    const float* __restrict__ kb_r, const float* __restrict__ kb_i,
    const float* __restrict__ vw_r, const float* __restrict__ vw_i,
    const float* __restrict__ vb_r, const float* __restrict__ vb_i,
    const float* __restrict__ gw_r, const float* __restrict__ gw_i,
    const float* __restrict__ gb_r, const float* __restrict__ gb_i,
    short* __restrict__ qp_r, short* __restrict__ qp_i,
    short* __restrict__ kp_r, short* __restrict__ kp_i,
    short* __restrict__ vpT_r, short* __restrict__ vpT_i,
    short* __restrict__ gp_r, short* __restrict__ gp_i)
{
    const int y = blockIdx.y;
    const float *xr, *xi, *wr, *wi, *br, *bi, *per = nullptr, *pei = nullptr;
    short *outr_, *outi_;
    int M, omode, col0;
    if (y < 4)      { xr = q_r; xi = q_i; wr = qw_r; wi = qw_i; br = qb_r; bi = qb_i;
                      per = pe_q_r; pei = pe_q_i; outr_ = qp_r; outi_ = qp_i;
                      M = 256; omode = 1; col0 = y * 64; }
    else if (y < 6) { xr = k_r; xi = k_i; wr = kw_r; wi = kw_i; br = kb_r; bi = kb_i;
                      per = pe_k_r; pei = pe_k_i; outr_ = kp_r; outi_ = kp_i;
                      M = 128; omode = 1; col0 = (y - 4) * 64; }
    else if (y < 8) { xr = v_r; xi = v_i; wr = vw_r; wi = vw_i; br = vb_r; bi = vb_i;
                      outr_ = vpT_r; outi_ = vpT_i;
                      M = 128; omode = 2; col0 = (y - 6) * 64; }
    else            { xr = q_r; xi = q_i; wr = gw_r; wi = gw_i; br = gb_r; bi = gb_i;
                      outr_ = gp_r; outi_ = gp_i;
                      M = 128; omode = 1; col0 = (y - 8) * 64; }

    __shared__ short As[64 * 72], Brs[64 * 72], Bis[64 * 72];
    const int t = threadIdx.x;
    const int row0 = blockIdx.x * 64;
    const int lane = t & 63, wid = t >> 6;
    const int wm = (wid >> 1) * 32, wn = (wid & 1) * 32;
    const int fm = lane & 15, fq = lane >> 4;
    f32x4 zero4 = {0.f, 0.f, 0.f, 0.f};
    f32x4 accr[2][2], acci[2][2];
    #pragma unroll
    for (int i = 0; i < 2; ++i)
        #pragma unroll
        for (int j = 0; j < 2; ++j) { accr[i][j] = zero4; acci[i][j] = zero4; }

    for (int c = 0; c < 4; ++c) {
        const bool hi = (c >= 2);
        const int kb = (c & 1) * 64;
        const float* Asrc = hi ? xi : xr;
        const float* Brsrc = hi ? wi : wr;
        const float* Bisrc = hi ? wr : wi;
        const float bsign = hi ? -1.0f : 1.0f;
        __syncthreads();
        #pragma unroll
        for (int it = 0; it < 4; ++it) {
            int lin = it * 256 + t;
            int r = lin >> 4, k4 = (lin & 15) * 4;
            float4 va = *(const float4*)&Asrc[(size_t)(row0 + r) * 128 + kb + k4];
            *(short4*)&As[r * 72 + k4] = make_short4(f2h(va.x), f2h(va.y), f2h(va.z), f2h(va.w));
            float4 vr = *(const float4*)&Brsrc[(size_t)(col0 + r) * 128 + kb + k4];
            *(short4*)&Brs[r * 72 + k4] = make_short4(f2h(bsign * vr.x), f2h(bsign * vr.y),
                                                      f2h(bsign * vr.z), f2h(bsign * vr.w));
            float4 vi = *(const float4*)&Bisrc[(size_t)(col0 + r) * 128 + kb + k4];
            *(short4*)&Bis[r * 72 + k4] = make_short4(f2h(vi.x), f2h(vi.y), f2h(vi.z), f2h(vi.w));
        }
        __syncthreads();
        #pragma unroll
        for (int ks = 0; ks < 64; ks += 32) {
            f16x8 bfr[2], bfi[2];
            #pragma unroll
            for (int j = 0; j < 2; ++j) {
                bfr[j] = *(const f16x8*)&Brs[(wn + j * 16 + fm) * 72 + ks + fq * 8];
                bfi[j] = *(const f16x8*)&Bis[(wn + j * 16 + fm) * 72 + ks + fq * 8];
            }
            #pragma unroll
            for (int i = 0; i < 2; ++i) {
                f16x8 a = *(const f16x8*)&As[(wm + i * 16 + fm) * 72 + ks + fq * 8];
                #pragma unroll
                for (int j = 0; j < 2; ++j) {
                    accr[i][j] = __builtin_amdgcn_mfma_f32_16x16x32_f16(a, bfr[j], accr[i][j], 0, 0, 0);
                    acci[i][j] = __builtin_amdgcn_mfma_f32_16x16x32_f16(a, bfi[j], acci[i][j], 0, 0, 0);
                }
            }
        }
    }
    #pragma unroll
    for (int i = 0; i < 2; ++i)
        #pragma unroll
        for (int j = 0; j < 2; ++j) {
            int colc = col0 + wn + j * 16 + fm;
            float bbr = br[colc], bbi = bi[colc];
            if (omode == 2) {
                int rb = row0 + wm + i * 16 + fq * 4;
                int hq = rb >> 10, sq = rb & 1023;
                short4 o_r4 = make_short4(f2h(accr[i][j][0] + bbr), f2h(accr[i][j][1] + bbr),
                                          f2h(accr[i][j][2] + bbr), f2h(accr[i][j][3] + bbr));
                short4 o_i4 = make_short4(f2h(acci[i][j][0] + bbi), f2h(acci[i][j][1] + bbi),
                                          f2h(acci[i][j][2] + bbi), f2h(acci[i][j][3] + bbi));
                size_t ob = ((size_t)(hq * 128 + colc)) * 1024 + sq;
                *(short4*)&outr_[ob] = o_r4;
                *(short4*)&outi_[ob] = o_i4;
            } else {
                #pragma unroll
                for (int reg = 0; reg < 4; ++reg) {
                    int rr = row0 + wm + i * 16 + fq * 4 + reg;
                    float o_r = accr[i][j][reg] + bbr;
                    float o_i = acci[i][j][reg] + bbi;
                    if (per) {
                        o_r += per[(size_t)rr * 128 + (colc & 127)];
                        o_i += pei[(size_t)rr * 128 + (colc & 127)];
                    }
                    outr_[(size_t)rr * M + colc] = f2h(o_r);
                    outi_[(size_t)rr * M + colc] = f2h(o_i);
                }
            }
        }
}

// ============================================================
// o-projection: fp16 gated input gp, fp32 weights, fp32 out. 64x64 tiles.
// (unchanged — proven r1 kernel)
// ============================================================
__global__ __launch_bounds__(256) void oproj_mfma(
    const short* __restrict__ gp_r, const short* __restrict__ gp_i,
    const float* __restrict__ wr, const float* __restrict__ wi,
    const float* __restrict__ br, const float* __restrict__ bi,
    float* __restrict__ outr, float* __restrict__ outi)
{
    __shared__ short As[64 * 72], Brs[64 * 72], Bis[64 * 72];
    const int t = threadIdx.x;
    const int row0 = blockIdx.x * 64, col0 = blockIdx.y * 64;
    const int lane = t & 63, wid = t >> 6;
    const int wm = (wid >> 1) * 32, wn = (wid & 1) * 32;
    const int fm = lane & 15, fq = lane >> 4;
    f32x4 zero4 = {0.f, 0.f, 0.f, 0.f};
    f32x4 accr[2][2], acci[2][2];
    #pragma unroll
    for (int i = 0; i < 2; ++i)
        #pragma unroll
        for (int j = 0; j < 2; ++j) { accr[i][j] = zero4; acci[i][j] = zero4; }

    for (int c = 0; c < 4; ++c) {
        const bool hi = (c >= 2);
        const int kb = (c & 1) * 64;
        const short* Asrc = hi ? gp_i : gp_r;
        const float* Brsrc = hi ? wi : wr;
        const float* Bisrc = hi ? wr : wi;
        const float bsign = hi ? -1.0f : 1.0f;
        __syncthreads();
        #pragma unroll
        for (int it = 0; it < 4; ++it) {
            int lin = it * 256 + t;
            int r = lin >> 4, k4 = (lin & 15) * 4;
            *(short4*)&As[r * 72 + k4] = *(const short4*)&Asrc[(size_t)(row0 + r) * 128 + kb + k4];
            float4 vr = *(const float4*)&Brsrc[(size_t)(col0 + r) * 128 + kb + k4];
            *(short4*)&Brs[r * 72 + k4] = make_short4(f2h(bsign * vr.x), f2h(bsign * vr.y),
                                                      f2h(bsign * vr.z), f2h(bsign * vr.w));
            float4 vi = *(const float4*)&Bisrc[(size_t)(col0 + r) * 128 + kb + k4];
            *(short4*)&Bis[r * 72 + k4] = make_short4(f2h(vi.x), f2h(vi.y), f2h(vi.z), f2h(vi.w));
        }
        __syncthreads();
        #pragma unroll
        for (int ks = 0; ks < 64; ks += 32) {
            f16x8 bfr[2], bfi[2];
            #pragma unroll
            for (int j = 0; j < 2; ++j) {
                bfr[j] = *(const f16x8*)&Brs[(wn + j * 16 + fm) * 72 + ks + fq * 8];
                bfi[j] = *(const f16x8*)&Bis[(wn + j * 16 + fm) * 72 + ks + fq * 8];
            }
            #pragma unroll
            for (int i = 0; i < 2; ++i) {
                f16x8 a = *(const f16x8*)&As[(wm + i * 16 + fm) * 72 + ks + fq * 8];
                #pragma unroll
                for (int j = 0; j < 2; ++j) {
                    accr[i][j] = __builtin_amdgcn_mfma_f32_16x16x32_f16(a, bfr[j], accr[i][j], 0, 0, 0);
                    acci[i][j] = __builtin_amdgcn_mfma_f32_16x16x32_f16(a, bfi[j], acci[i][j], 0, 0, 0);
                }
            }
        }
    }
    #pragma unroll
    for (int i = 0; i < 2; ++i)
        #pragma unroll
        for (int j = 0; j < 2; ++j) {
            int colc = col0 + wn + j * 16 + fm;
            float bbr = br[colc], bbi = bi[colc];
            #pragma unroll
            for (int reg = 0; reg < 4; ++reg) {
                int rr = row0 + wm + i * 16 + fq * 4 + reg;
                outr[(size_t)rr * 128 + colc] = accr[i][j][reg] + bbr;
                outi[(size_t)rr * 128 + colc] = acci[i][j][reg] + bbi;
            }
        }
}

// ============================================================
// Scores v2: 64q x 128k tile, K-dim (=d) chunk 64. Kr AND Ki resident
// in LDS simultaneously (36.9KB, same as before) -> 2 barriers per kb
// instead of 4, no K re-stage. Q fragments loaded DIRECTLY from global
// (L2-resident qp) into regs -> no Q LDS round-trip. 16B staging loads.
// Math/fragment patterns identical to proven r1 score_mfma.
// ============================================================
__global__ __launch_bounds__(256) void score_mfma(
    const short* __restrict__ qp_r, const short* __restrict__ qp_i,
    const short* __restrict__ kp_r, const short* __restrict__ kp_i,
    short* __restrict__ w16, int h0)
{
    __shared__ short Kr[128 * 72], Ki[128 * 72];
    const int t = threadIdx.x;
    const int hh = blockIdx.z >> 1, map = blockIdx.z & 1;
    const int h = h0 + hh;
    const int q0 = blockIdx.x * 64, c0 = blockIdx.y * 128;
    const int lane = t & 63, wid = t >> 6;
    const int wm = (wid >> 1) * 32, wn = (wid & 1) * 64;
    const int fm = lane & 15, fq = lane >> 4;
    f32x4 zero4 = {0.f, 0.f, 0.f, 0.f};
    f32x4 sr[2][4], si[2][4];
    #pragma unroll
    for (int i = 0; i < 2; ++i)
        #pragma unroll
        for (int j = 0; j < 4; ++j) { sr[i][j] = zero4; si[i][j] = zero4; }

    for (int kb = 0; kb < 2; ++kb) {
        __syncthreads(); // prev kb's MFMAs done reading Kr/Ki
        // stage Kr,Ki: 128 k-rows x 64 d-cols, 16B loads (4 iters x 2)
        #pragma unroll
        for (int i = 0; i < 4; ++i) {
            int lin = i * 256 + t;              // 0..1023
            int r = lin >> 3, c8 = (lin & 7) * 8; // 128 rows x 64 cols
            size_t src = (size_t)(h * S + c0 + r) * 128 + kb * 64 + c8;
            *(i32x4*)&Kr[r * 72 + c8] = *(const i32x4*)&kp_r[src];
            *(i32x4*)&Ki[r * 72 + c8] = *(const i32x4*)&kp_i[src];
        }
        // Q fragments direct global->reg (independent of LDS staging)
        f16x8 aR[2][2], aI[2][2]; // [ks][i]
        #pragma unroll
        for (int ks = 0; ks < 2; ++ks)
            #pragma unroll
            for (int i = 0; i < 2; ++i) {
                size_t qa = (size_t)(h * S + q0 + wm + i * 16 + fm) * 256
                            + map * 128 + kb * 64 + ks * 32 + fq * 8;
                aR[ks][i] = *(const f16x8*)&qp_r[qa];
                aI[ks][i] = *(const f16x8*)&qp_i[qa];
            }
        __syncthreads();
        // complex QK^T: sr = qr.kr + qi.ki ; si = qi.kr - qr.ki
        #pragma unroll
        for (int ks = 0; ks < 2; ++ks) {
            f16x8 nR0 = fneg8(aR[ks][0]), nR1 = fneg8(aR[ks][1]);
            #pragma unroll
            for (int j = 0; j < 4; ++j) {
                int bo = (wn + j * 16 + fm) * 72 + ks * 32 + fq * 8;
                f16x8 bR = *(const f16x8*)&Kr[bo];
                f16x8 bI = *(const f16x8*)&Ki[bo];
                sr[0][j] = __builtin_amdgcn_mfma_f32_16x16x32_f16(aR[ks][0], bR, sr[0][j], 0, 0, 0);
                si[0][j] = __builtin_amdgcn_mfma_f32_16x16x32_f16(aI[ks][0], bR, si[0][j], 0, 0, 0);
                sr[0][j] = __builtin_amdgcn_mfma_f32_16x16x32_f16(aI[ks][0], bI, sr[0][j], 0, 0, 0);
                si[0][j] = __builtin_amdgcn_mfma_f32_16x16x32_f16(nR0, bI, si[0][j], 0, 0, 0);
                sr[1][j] = __builtin_amdgcn_mfma_f32_16x16x32_f16(aR[ks][1], bR, sr[1][j], 0, 0, 0);
                si[1][j] = __builtin_amdgcn_mfma_f32_16x16x32_f16(aI[ks][1], bR, si[1][j], 0, 0, 0);
                sr[1][j] = __builtin_amdgcn_mfma_f32_16x16x32_f16(aI[ks][1], bI, sr[1][j], 0, 0, 0);
                si[1][j] = __builtin_amdgcn_mfma_f32_16x16x32_f16(nR1, bI, si[1][j], 0, 0, 0);
            }
        }
    }
    const float scale = 0.08838834764831845f;
    #pragma unroll
    for (int i = 0; i < 2; ++i)
        #pragma unroll
        for (int j = 0; j < 4; ++j) {
            int kcol = c0 + wn + j * 16 + fm;
            #pragma unroll
            for (int reg = 0; reg < 4; ++reg) {
                int q = q0 + wm + i * 16 + fq * 4 + reg;
                float r1 = sr[i][j][reg], I1 = si[i][j][reg];
                float m1 = sqrtf(fmaf(r1, r1, fmaf(I1, I1, 1e-8f))) * scale;
                w16[(((size_t)hh * 2 + map) * S + q) * S + kcol] = f2h(m1);
            }
        }
}

// ============================================================
// AV with ONLINE softmax (smstats fused away): 32q x full 128d, both maps,
// one complex comp per block. Per 64-k chunk: read mags, per-row 16-lane
// reduce (max,sum), update running m/l in LDS, write P=exp(x-m_new) to LDS,
// rescale accO by exp(m_old-m_new), PV MFMA. Divide by l at epilogue.
// Kills the smstats dispatch + its 50MB w16 read.
// PV fragment patterns identical to proven r1 av_mfma.
// ============================================================
__global__ __launch_bounds__(256) void av_online(
    const short* __restrict__ w16,
    const short* __restrict__ vpT_r, const short* __restrict__ vpT_i,
    short* __restrict__ acat_r, short* __restrict__ acat_i, int h0)
{
    __shared__ short W1[32 * 72], W2[32 * 72], Vc[128 * 72];
    __shared__ float mrun[2][32], lrun[2][32], scL[2][32];
    const int t = threadIdx.x;
    const int hh = blockIdx.z, h = h0 + hh;
    const int comp = blockIdx.y;
    const int q0 = blockIdx.x * 32;
    const short* vpT = comp ? vpT_i : vpT_r;
    short* acat = comp ? acat_i : acat_r;
    const int lane = t & 63, wid = t >> 6;
    const int wm = (wid >> 1) * 16, wn = (wid & 1) * 64;
    const int fm = lane & 15, fq = lane >> 4;
    f32x4 zero4 = {0.f, 0.f, 0.f, 0.f};
    f32x4 a1[4], a2[4];
    #pragma unroll
    for (int j = 0; j < 4; ++j) { a1[j] = zero4; a2[j] = zero4; }
    if (t < 32) {
        mrun[0][t] = -3.0e38f; lrun[0][t] = 0.f;
        mrun[1][t] = -3.0e38f; lrun[1][t] = 0.f;
    }

    for (int k0 = 0; k0 < S; k0 += 64) {
        __syncthreads(); // prev PV done reading W/V; init/scL consumed
        // ---- stage W with online softmax update ----
        #pragma unroll
        for (int it = 0; it < 2; ++it) {
            int lin = it * 256 + t;
            int r = lin >> 4, k4 = (lin & 15) * 4; // 16 consecutive lanes per row
            short4 m1 = *(const short4*)&w16[(((size_t)hh * 2 + 0) * S + q0 + r) * S + k0 + k4];
            short4 m2 = *(const short4*)&w16[(((size_t)hh * 2 + 1) * S + q0 + r) * S + k0 + k4];
            float f10 = h2f(m1.x), f11 = h2f(m1.y), f12 = h2f(m1.z), f13 = h2f(m1.w);
            float f20 = h2f(m2.x), f21 = h2f(m2.y), f22 = h2f(m2.z), f23 = h2f(m2.w);
            // map1
            float mx1 = fmaxf(fmaxf(f10, f11), fmaxf(f12, f13));
            #pragma unroll
            for (int off = 1; off < 16; off <<= 1) mx1 = fmaxf(mx1, __shfl_xor(mx1, off));
            float mo1 = mrun[0][r];
            float mn1 = fmaxf(mo1, mx1);
            float e10 = __expf(f10 - mn1), e11 = __expf(f11 - mn1);
            float e12 = __expf(f12 - mn1), e13 = __expf(f13 - mn1);
            float s1 = e10 + e11 + e12 + e13;
            #pragma unroll
            for (int off = 1; off < 16; off <<= 1) s1 += __shfl_xor(s1, off);
            // map2
            float mx2 = fmaxf(fmaxf(f20, f21), fmaxf(f22, f23));
            #pragma unroll
            for (int off = 1; off < 16; off <<= 1) mx2 = fmaxf(mx2, __shfl_xor(mx2, off));
            float mo2 = mrun[1][r];
            float mn2 = fmaxf(mo2, mx2);
            float e20 = __expf(f20 - mn2), e21 = __expf(f21 - mn2);
            float e22 = __expf(f22 - mn2), e23 = __expf(f23 - mn2);
            float s2 = e20 + e21 + e22 + e23;
            #pragma unroll
            for (int off = 1; off < 16; off <<= 1) s2 += __shfl_xor(s2, off);
            if ((t & 15) == 0) { // one lane per row updates running stats
                float sc1 = __expf(mo1 - mn1);
                mrun[0][r] = mn1; scL[0][r] = sc1;
                lrun[0][r] = lrun[0][r] * sc1 + s1;
                float sc2 = __expf(mo2 - mn2);
                mrun[1][r] = mn2; scL[1][r] = sc2;
                lrun[1][r] = lrun[1][r] * sc2 + s2;
            }
            *(short4*)&W1[r * 72 + k4] = make_short4(f2h(e10), f2h(e11), f2h(e12), f2h(e13));
            *(short4*)&W2[r * 72 + k4] = make_short4(f2h(e20), f2h(e21), f2h(e22), f2h(e23));
        }
        // ---- stage V ----
        #pragma unroll
        for (int it = 0; it < 8; ++it) {
            int lin = it * 256 + t;
            int dd = lin >> 4, k4v = (lin & 15) * 4;
            *(short4*)&Vc[dd * 72 + k4v] = *(const short4*)&vpT[(size_t)(h * 128 + dd) * 1024 + k0 + k4v];
        }
        __syncthreads();
        // ---- rescale accO by scL ----
        float s1v[4], s2v[4];
        #pragma unroll
        for (int reg = 0; reg < 4; ++reg) {
            s1v[reg] = scL[0][wm + fq * 4 + reg];
            s2v[reg] = scL[1][wm + fq * 4 + reg];
        }
        #pragma unroll
        for (int j = 0; j < 4; ++j)
            #pragma unroll
            for (int reg = 0; reg < 4; ++reg) {
                a1[j][reg] *= s1v[reg];
                a2[j][reg] *= s2v[reg];
            }
        // ---- PV MFMA (proven av pattern) ----
        #pragma unroll
        for (int ks = 0; ks < 64; ks += 32) {
            f16x8 b[4];
            #pragma unroll
            for (int j = 0; j < 4; ++j)
                b[j] = *(const f16x8*)&Vc[(wn + j * 16 + fm) * 72 + ks + fq * 8];
            int wo = (wm + fm) * 72 + ks + fq * 8;
            f16x8 w1f = *(const f16x8*)&W1[wo];
            f16x8 w2f = *(const f16x8*)&W2[wo];
            #pragma unroll
            for (int j = 0; j < 4; ++j) {
                a1[j] = __builtin_amdgcn_mfma_f32_16x16x32_f16(w1f, b[j], a1[j], 0, 0, 0);
                a2[j] = __builtin_amdgcn_mfma_f32_16x16x32_f16(w2f, b[j], a2[j], 0, 0, 0);
            }
        }
    }
    // ---- epilogue: divide by running sum ----
    float invl1[4], invl2[4];
    #pragma unroll
    for (int reg = 0; reg < 4; ++reg) {
        invl1[reg] = 1.0f / lrun[0][wm + fq * 4 + reg];
        invl2[reg] = 1.0f / lrun[1][wm + fq * 4 + reg];
    }
    #pragma unroll
    for (int j = 0; j < 4; ++j) {
        int d = wn + j * 16 + fm;
        #pragma unroll
        for (int reg = 0; reg < 4; ++reg) {
            int q = q0 + wm + fq * 4 + reg;
            size_t rowb = (size_t)(h * S + q) * 256;
            acat[rowb + d]       = f2h(a1[j][reg] * invl1[reg]);
            acat[rowb + 128 + d] = f2h(a2[j][reg] * invl2[reg]);
        }
    }
}

// ============================================================
// RMS over 256 complex + sub_w + (a1 - lam*a2) + complex gate.
// (unchanged — proven r1 kernel)
// ============================================================
__global__ __launch_bounds__(256) void rmsgate_kernel(
    const short* __restrict__ acat_r, const short* __restrict__ acat_i,
    const float* __restrict__ sub_w, const float* __restrict__ lam_ptr,
    short* __restrict__ gp_r, short* __restrict__ gp_i)
{
    int row = blockIdx.x;
    int t = threadIdx.x;
    float ar = h2f(acat_r[(size_t)row * 256 + t]);
    float ai = h2f(acat_i[(size_t)row * 256 + t]);
    float ss = fmaf(ar, ar, ai * ai);
    #pragma unroll
    for (int off = 32; off; off >>= 1) ss += __shfl_xor(ss, off);
    __shared__ float red[4];
    if ((t & 63) == 0) red[t >> 6] = ss;
    __syncthreads();
    float total = red[0] + red[1] + red[2] + red[3];
    float inv_rms = 1.0f / sqrtf(total * (1.0f / 256.0f) + 1e-5f);
    float sw = sub_w[t];
    __shared__ float Cr[256], Ci[256];
    Cr[t] = ar * inv_rms * sw;
    Ci[t] = ai * inv_rms * sw;
    __syncthreads();
    if (t < 128) {
        float lam = lam_ptr[0];
        float o_r = Cr[t] - lam * Cr[t + 128];
        float o_i = Ci[t] - lam * Ci[t + 128];
        float gr = h2f(gp_r[(size_t)row * 128 + t]);
        float gi = h2f(gp_i[(size_t)row * 128 + t]);
        gp_r[(size_t)row * 128 + t] = f2h(gr * o_r - gi * o_i);
        gp_i[(size_t)row * 128 + t] = f2h(gr * o_i + gi * o_r);
    }
}

// ============================================================
extern "C" void kernel_launch(void* const* d_in, const int* in_sizes, int n_in,
                              void* d_out, int out_size, void* d_ws, size_t ws_size,
                              hipStream_t stream)
{
    (void)in_sizes; (void)n_in; (void)out_size;
    const float* q_r    = (const float*)d_in[0];
    const float* q_i    = (const float*)d_in[1];
    const float* k_r    = (const float*)d_in[2];
    const float* k_i    = (const float*)d_in[3];
    const float* v_r    = (const float*)d_in[4];
    const float* v_i    = (const float*)d_in[5];
    const float* pe_q_r = (const float*)d_in[6];
    const float* pe_q_i = (const float*)d_in[7];
    const float* pe_k_r = (const float*)d_in[8];
    const float* pe_k_i = (const float*)d_in[9];
    const float* qw_r   = (const float*)d_in[10];
    const float* qw_i   = (const float*)d_in[11];
    const float* qb_r   = (const float*)d_in[12];
    const float* qb_i   = (const float*)d_in[13];
    const float* kw_r   = (const float*)d_in[14];
    const float* kw_i   = (const float*)d_in[15];
    const float* kb_r   = (const float*)d_in[16];
    const float* kb_i   = (const float*)d_in[17];
    const float* vw_r   = (const float*)d_in[18];
    const float* vw_i   = (const float*)d_in[19];
    const float* vb_r   = (const float*)d_in[20];
    const float* vb_i   = (const float*)d_in[21];
    const float* gw_r   = (const float*)d_in[22];
    const float* gw_i   = (const float*)d_in[23];
    const float* gb_r   = (const float*)d_in[24];
    const float* gb_i   = (const float*)d_in[25];
    const float* ow_r   = (const float*)d_in[26];
    const float* ow_i   = (const float*)d_in[27];
    const float* ob_r   = (const float*)d_in[28];
    const float* ob_i   = (const float*)d_in[29];
    const float* lq1    = (const float*)d_in[30];
    const float* lk1    = (const float*)d_in[31];
    const float* lq2    = (const float*)d_in[32];
    const float* lk2    = (const float*)d_in[33];
    const float* sub_w  = (const float*)d_in[34];

    char* ws = (char*)d_ws;
    short* qp_r   = (short*)(ws + WS_QP_R);
    short* qp_i   = (short*)(ws + WS_QP_I);
    short* kp_r   = (short*)(ws + WS_KP_R);
    short* kp_i   = (short*)(ws + WS_KP_I);
    short* vpT_r  = (short*)(ws + WS_VPT_R);
    short* vpT_i  = (short*)(ws + WS_VPT_I);
    short* gp_r   = (short*)(ws + WS_GP_R);
    short* gp_i   = (short*)(ws + WS_GP_I);
    short* acat_r = (short*)(ws + WS_ACAT_R);
    short* acat_i = (short*)(ws + WS_ACAT_I);
    float* lam    = (float*)(ws + WS_LAM);
    short* w16    = (short*)(ws + WS_SC);

    float* out_r = (float*)d_out;
    float* out_i = out_r + (size_t)NROWS * D;

    // head-chunking by workspace (depends only on ws_size -> graph-safe)
    size_t avail = ws_size > WS_SC ? ws_size - WS_SC : 0;
    int nh_chunk = (int)(avail / W16_PER_HEAD);
    if (nh_chunk < 1) nh_chunk = 1;
    if (nh_chunk > H) nh_chunk = H;

    lam_kernel<<<1, 128, 0, stream>>>(lq1, lk1, lq2, lk2, lam);

    // ALL projections in one dispatch (q/k -> fp16 +PE; v -> fp16 T; g -> fp16)
    proj_all<<<dim3(192, 10), 256, 0, stream>>>(
        q_r, q_i, k_r, k_i, v_r, v_i, pe_q_r, pe_q_i, pe_k_r, pe_k_i,
        qw_r, qw_i, qb_r, qb_i, kw_r, kw_i, kb_r, kb_i,
        vw_r, vw_i, vb_r, vb_i, gw_r, gw_i, gb_r, gb_i,
        qp_r, qp_i, kp_r, kp_i, vpT_r, vpT_i, gp_r, gp_i);

    for (int h0 = 0; h0 < H; h0 += nh_chunk) {
        int nhh = (H - h0 < nh_chunk) ? (H - h0) : nh_chunk;
        score_mfma<<<dim3(16, 8, nhh * 2), 256, 0, stream>>>(qp_r, qp_i, kp_r, kp_i, w16, h0);
        av_online<<<dim3(32, 2, nhh), 256, 0, stream>>>(w16, vpT_r, vpT_i, acat_r, acat_i, h0);
    }

    rmsgate_kernel<<<NROWS, 256, 0, stream>>>(acat_r, acat_i, sub_w, lam, gp_r, gp_i);

    oproj_mfma<<<dim3(192, 2), 256, 0, stream>>>(gp_r, gp_i, ow_r, ow_i, ob_r, ob_i, out_r, out_i);
}

// Round 4
// 317.420 us; speedup vs baseline: 1.8123x; 1.0895x over previous
//
#include <hip/hip_runtime.h>
#include <math.h>

#define H 12
#define S 1024
#define D 128
#define NROWS (H * S) // 12288

typedef __attribute__((ext_vector_type(8))) _Float16 f16x8; // 8 fp16 in 4 VGPRs
typedef __attribute__((ext_vector_type(4))) float f32x4;
typedef __attribute__((ext_vector_type(4))) int i32x4;

__device__ __forceinline__ short f2h(float f) { // RNE float->fp16, bits as short
    _Float16 h = (_Float16)f;
    return __builtin_bit_cast(short, h);
}
__device__ __forceinline__ float h2f(short s) {
    return (float)__builtin_bit_cast(_Float16, s);
}
__device__ __forceinline__ f16x8 fneg8(f16x8 v) { // packed sign flip
    i32x4 u = __builtin_bit_cast(i32x4, v);
    u ^= (int)0x80008000;
    return __builtin_bit_cast(f16x8, u);
}

// ---- workspace layout (BYTE offsets) ----
// qp fp16 [12288][256] r/i ; kp fp16 [12288][128] r/i ; vpT fp16 [H][128][1024] r/i
// gp fp16 [12288][128] r/i ; acat fp16 [12288][256] r/i ; lam ;
// w16 fp16 per chunk-head 2*S*S ; stats float2 per chunk-head 2*S
#define WS_QP_R   0ULL
#define WS_QP_I   6291456ULL
#define WS_KP_R   12582912ULL
#define WS_KP_I   15728640ULL
#define WS_VPT_R  18874368ULL
#define WS_VPT_I  22020096ULL
#define WS_GP_R   25165824ULL
#define WS_GP_I   28311552ULL
#define WS_ACAT_R 31457280ULL
#define WS_ACAT_I 37748736ULL
#define WS_LAM    44040192ULL
#define WS_SC     44040448ULL
#define W16_PER_HEAD   4194304ULL // 2*1024*1024*2B
#define STAT_PER_HEAD  16384ULL   // 2*1024*8B

// ============================================================
__global__ void lam_kernel(const float* __restrict__ lq1, const float* __restrict__ lk1,
                           const float* __restrict__ lq2, const float* __restrict__ lk2,
                           float* __restrict__ lam_out)
{
    int t = threadIdx.x; // 128 threads
    float p1 = lq1[t] * lk1[t];
    float p2 = lq2[t] * lk2[t];
    #pragma unroll
    for (int off = 32; off; off >>= 1) {
        p1 += __shfl_xor(p1, off);
        p2 += __shfl_xor(p2, off);
    }
    __shared__ float s1[2], s2[2];
    if ((t & 63) == 0) { s1[t >> 6] = p1; s2[t >> 6] = p2; }
    __syncthreads();
    if (t == 0) {
        float l1 = expf(s1[0] + s1[1]);
        float l2 = expf(s2[0] + s2[1]);
        float x = l1 - l2 + 0.3555090675909693f; // 0.8 - 0.6*exp(-0.3)
        lam_out[0] = 1.0f / (1.0f + expf(-x));
    }
}

// ============================================================
// ALL FOUR projections in ONE dispatch. grid = (192, 10), 64x64 tiles.
// (unchanged — proven r1 kernel)
// ============================================================
__global__ __launch_bounds__(256) void proj_all(
    const float* __restrict__ q_r, const float* __restrict__ q_i,
    const float* __restrict__ k_r, const float* __restrict__ k_i,
    const float* __restrict__ v_r, const float* __restrict__ v_i,
    const float* __restrict__ pe_q_r, const float* __restrict__ pe_q_i,
    const float* __restrict__ pe_k_r, const float* __restrict__ pe_k_i,
    const float* __restrict__ qw_r, const float* __restrict__ qw_i,
    const float* __restrict__ qb_r, const float* __restrict__ qb_i,
    const float* __restrict__ kw_r, const float* __restrict__ kw_i,
    const float* __restrict__ kb_r, const float* __restrict__ kb_i,
    const float* __restrict__ vw_r, const float* __restrict__ vw_i,
    const float* __restrict__ vb_r, const float* __restrict__ vb_i,
    const float* __restrict__ gw_r, const float* __restrict__ gw_i,
    const float* __restrict__ gb_r, const float* __restrict__ gb_i,
    short* __restrict__ qp_r, short* __restrict__ qp_i,
    short* __restrict__ kp_r, short* __restrict__ kp_i,
    short* __restrict__ vpT_r, short* __restrict__ vpT_i,
    short* __restrict__ gp_r, short* __restrict__ gp_i)
{
    const int y = blockIdx.y;
    const float *xr, *xi, *wr, *wi, *br, *bi, *per = nullptr, *pei = nullptr;
    short *outr_, *outi_;
    int M, omode, col0;
    if (y < 4)      { xr = q_r; xi = q_i; wr = qw_r; wi = qw_i; br = qb_r; bi = qb_i;
                      per = pe_q_r; pei = pe_q_i; outr_ = qp_r; outi_ = qp_i;
                      M = 256; omode = 1; col0 = y * 64; }
    else if (y < 6) { xr = k_r; xi = k_i; wr = kw_r; wi = kw_i; br = kb_r; bi = kb_i;
                      per = pe_k_r; pei = pe_k_i; outr_ = kp_r; outi_ = kp_i;
                      M = 128; omode = 1; col0 = (y - 4) * 64; }
    else if (y < 8) { xr = v_r; xi = v_i; wr = vw_r; wi = vw_i; br = vb_r; bi = vb_i;
                      outr_ = vpT_r; outi_ = vpT_i;
                      M = 128; omode = 2; col0 = (y - 6) * 64; }
    else            { xr = q_r; xi = q_i; wr = gw_r; wi = gw_i; br = gb_r; bi = gb_i;
                      outr_ = gp_r; outi_ = gp_i;
                      M = 128; omode = 1; col0 = (y - 8) * 64; }

    __shared__ short As[64 * 72], Brs[64 * 72], Bis[64 * 72];
    const int t = threadIdx.x;
    const int row0 = blockIdx.x * 64;
    const int lane = t & 63, wid = t >> 6;
    const int wm = (wid >> 1) * 32, wn = (wid & 1) * 32;
    const int fm = lane & 15, fq = lane >> 4;
    f32x4 zero4 = {0.f, 0.f, 0.f, 0.f};
    f32x4 accr[2][2], acci[2][2];
    #pragma unroll
    for (int i = 0; i < 2; ++i)
        #pragma unroll
        for (int j = 0; j < 2; ++j) { accr[i][j] = zero4; acci[i][j] = zero4; }

    for (int c = 0; c < 4; ++c) {
        const bool hi = (c >= 2);
        const int kb = (c & 1) * 64;
        const float* Asrc = hi ? xi : xr;
        const float* Brsrc = hi ? wi : wr;
        const float* Bisrc = hi ? wr : wi;
        const float bsign = hi ? -1.0f : 1.0f;
        __syncthreads();
        #pragma unroll
        for (int it = 0; it < 4; ++it) {
            int lin = it * 256 + t;
            int r = lin >> 4, k4 = (lin & 15) * 4;
            float4 va = *(const float4*)&Asrc[(size_t)(row0 + r) * 128 + kb + k4];
            *(short4*)&As[r * 72 + k4] = make_short4(f2h(va.x), f2h(va.y), f2h(va.z), f2h(va.w));
            float4 vr = *(const float4*)&Brsrc[(size_t)(col0 + r) * 128 + kb + k4];
            *(short4*)&Brs[r * 72 + k4] = make_short4(f2h(bsign * vr.x), f2h(bsign * vr.y),
                                                      f2h(bsign * vr.z), f2h(bsign * vr.w));
            float4 vi = *(const float4*)&Bisrc[(size_t)(col0 + r) * 128 + kb + k4];
            *(short4*)&Bis[r * 72 + k4] = make_short4(f2h(vi.x), f2h(vi.y), f2h(vi.z), f2h(vi.w));
        }
        __syncthreads();
        #pragma unroll
        for (int ks = 0; ks < 64; ks += 32) {
            f16x8 bfr[2], bfi[2];
            #pragma unroll
            for (int j = 0; j < 2; ++j) {
                bfr[j] = *(const f16x8*)&Brs[(wn + j * 16 + fm) * 72 + ks + fq * 8];
                bfi[j] = *(const f16x8*)&Bis[(wn + j * 16 + fm) * 72 + ks + fq * 8];
            }
            #pragma unroll
            for (int i = 0; i < 2; ++i) {
                f16x8 a = *(const f16x8*)&As[(wm + i * 16 + fm) * 72 + ks + fq * 8];
                #pragma unroll
                for (int j = 0; j < 2; ++j) {
                    accr[i][j] = __builtin_amdgcn_mfma_f32_16x16x32_f16(a, bfr[j], accr[i][j], 0, 0, 0);
                    acci[i][j] = __builtin_amdgcn_mfma_f32_16x16x32_f16(a, bfi[j], acci[i][j], 0, 0, 0);
                }
            }
        }
    }
    #pragma unroll
    for (int i = 0; i < 2; ++i)
        #pragma unroll
        for (int j = 0; j < 2; ++j) {
            int colc = col0 + wn + j * 16 + fm;
            float bbr = br[colc], bbi = bi[colc];
            if (omode == 2) {
                int rb = row0 + wm + i * 16 + fq * 4;
                int hq = rb >> 10, sq = rb & 1023;
                short4 o_r4 = make_short4(f2h(accr[i][j][0] + bbr), f2h(accr[i][j][1] + bbr),
                                          f2h(accr[i][j][2] + bbr), f2h(accr[i][j][3] + bbr));
                short4 o_i4 = make_short4(f2h(acci[i][j][0] + bbi), f2h(acci[i][j][1] + bbi),
                                          f2h(acci[i][j][2] + bbi), f2h(acci[i][j][3] + bbi));
                size_t ob = ((size_t)(hq * 128 + colc)) * 1024 + sq;
                *(short4*)&outr_[ob] = o_r4;
                *(short4*)&outi_[ob] = o_i4;
            } else {
                #pragma unroll
                for (int reg = 0; reg < 4; ++reg) {
                    int rr = row0 + wm + i * 16 + fq * 4 + reg;
                    float o_r = accr[i][j][reg] + bbr;
                    float o_i = acci[i][j][reg] + bbi;
                    if (per) {
                        o_r += per[(size_t)rr * 128 + (colc & 127)];
                        o_i += pei[(size_t)rr * 128 + (colc & 127)];
                    }
                    outr_[(size_t)rr * M + colc] = f2h(o_r);
                    outi_[(size_t)rr * M + colc] = f2h(o_i);
                }
            }
        }
}

// ============================================================
// o-projection: fp16 gated input gp, fp32 weights, fp32 out. 64x64 tiles.
// (unchanged — proven r1 kernel)
// ============================================================
__global__ __launch_bounds__(256) void oproj_mfma(
    const short* __restrict__ gp_r, const short* __restrict__ gp_i,
    const float* __restrict__ wr, const float* __restrict__ wi,
    const float* __restrict__ br, const float* __restrict__ bi,
    float* __restrict__ outr, float* __restrict__ outi)
{
    __shared__ short As[64 * 72], Brs[64 * 72], Bis[64 * 72];
    const int t = threadIdx.x;
    const int row0 = blockIdx.x * 64, col0 = blockIdx.y * 64;
    const int lane = t & 63, wid = t >> 6;
    const int wm = (wid >> 1) * 32, wn = (wid & 1) * 32;
    const int fm = lane & 15, fq = lane >> 4;
    f32x4 zero4 = {0.f, 0.f, 0.f, 0.f};
    f32x4 accr[2][2], acci[2][2];
    #pragma unroll
    for (int i = 0; i < 2; ++i)
        #pragma unroll
        for (int j = 0; j < 2; ++j) { accr[i][j] = zero4; acci[i][j] = zero4; }

    for (int c = 0; c < 4; ++c) {
        const bool hi = (c >= 2);
        const int kb = (c & 1) * 64;
        const short* Asrc = hi ? gp_i : gp_r;
        const float* Brsrc = hi ? wi : wr;
        const float* Bisrc = hi ? wr : wi;
        const float bsign = hi ? -1.0f : 1.0f;
        __syncthreads();
        #pragma unroll
        for (int it = 0; it < 4; ++it) {
            int lin = it * 256 + t;
            int r = lin >> 4, k4 = (lin & 15) * 4;
            *(short4*)&As[r * 72 + k4] = *(const short4*)&Asrc[(size_t)(row0 + r) * 128 + kb + k4];
            float4 vr = *(const float4*)&Brsrc[(size_t)(col0 + r) * 128 + kb + k4];
            *(short4*)&Brs[r * 72 + k4] = make_short4(f2h(bsign * vr.x), f2h(bsign * vr.y),
                                                      f2h(bsign * vr.z), f2h(bsign * vr.w));
            float4 vi = *(const float4*)&Bisrc[(size_t)(col0 + r) * 128 + kb + k4];
            *(short4*)&Bis[r * 72 + k4] = make_short4(f2h(vi.x), f2h(vi.y), f2h(vi.z), f2h(vi.w));
        }
        __syncthreads();
        #pragma unroll
        for (int ks = 0; ks < 64; ks += 32) {
            f16x8 bfr[2], bfi[2];
            #pragma unroll
            for (int j = 0; j < 2; ++j) {
                bfr[j] = *(const f16x8*)&Brs[(wn + j * 16 + fm) * 72 + ks + fq * 8];
                bfi[j] = *(const f16x8*)&Bis[(wn + j * 16 + fm) * 72 + ks + fq * 8];
            }
            #pragma unroll
            for (int i = 0; i < 2; ++i) {
                f16x8 a = *(const f16x8*)&As[(wm + i * 16 + fm) * 72 + ks + fq * 8];
                #pragma unroll
                for (int j = 0; j < 2; ++j) {
                    accr[i][j] = __builtin_amdgcn_mfma_f32_16x16x32_f16(a, bfr[j], accr[i][j], 0, 0, 0);
                    acci[i][j] = __builtin_amdgcn_mfma_f32_16x16x32_f16(a, bfi[j], acci[i][j], 0, 0, 0);
                }
            }
        }
    }
    #pragma unroll
    for (int i = 0; i < 2; ++i)
        #pragma unroll
        for (int j = 0; j < 2; ++j) {
            int colc = col0 + wn + j * 16 + fm;
            float bbr = br[colc], bbi = bi[colc];
            #pragma unroll
            for (int reg = 0; reg < 4; ++reg) {
                int rr = row0 + wm + i * 16 + fq * 4 + reg;
                outr[(size_t)rr * 128 + colc] = accr[i][j][reg] + bbr;
                outi[(size_t)rr * 128 + colc] = acci[i][j][reg] + bbi;
            }
        }
}

// ============================================================
// Scores v2 (verified r3): 64q x 128k tile, d-chunk 64. Kr AND Ki resident
// in LDS simultaneously -> 2 barriers per kb instead of 4, no K re-stage.
// Q fragments loaded DIRECTLY from global (L2-resident qp) into regs.
// ============================================================
__global__ __launch_bounds__(256) void score_mfma(
    const short* __restrict__ qp_r, const short* __restrict__ qp_i,
    const short* __restrict__ kp_r, const short* __restrict__ kp_i,
    short* __restrict__ w16, int h0)
{
    __shared__ short Kr[128 * 72], Ki[128 * 72];
    const int t = threadIdx.x;
    const int hh = blockIdx.z >> 1, map = blockIdx.z & 1;
    const int h = h0 + hh;
    const int q0 = blockIdx.x * 64, c0 = blockIdx.y * 128;
    const int lane = t & 63, wid = t >> 6;
    const int wm = (wid >> 1) * 32, wn = (wid & 1) * 64;
    const int fm = lane & 15, fq = lane >> 4;
    f32x4 zero4 = {0.f, 0.f, 0.f, 0.f};
    f32x4 sr[2][4], si[2][4];
    #pragma unroll
    for (int i = 0; i < 2; ++i)
        #pragma unroll
        for (int j = 0; j < 4; ++j) { sr[i][j] = zero4; si[i][j] = zero4; }

    for (int kb = 0; kb < 2; ++kb) {
        __syncthreads(); // prev kb's MFMAs done reading Kr/Ki
        // stage Kr,Ki: 128 k-rows x 64 d-cols, 16B loads
        #pragma unroll
        for (int i = 0; i < 4; ++i) {
            int lin = i * 256 + t;              // 0..1023
            int r = lin >> 3, c8 = (lin & 7) * 8; // 128 rows x 64 cols
            size_t src = (size_t)(h * S + c0 + r) * 128 + kb * 64 + c8;
            *(i32x4*)&Kr[r * 72 + c8] = *(const i32x4*)&kp_r[src];
            *(i32x4*)&Ki[r * 72 + c8] = *(const i32x4*)&kp_i[src];
        }
        // Q fragments direct global->reg (independent of LDS staging)
        f16x8 aR[2][2], aI[2][2]; // [ks][i]
        #pragma unroll
        for (int ks = 0; ks < 2; ++ks)
            #pragma unroll
            for (int i = 0; i < 2; ++i) {
                size_t qa = (size_t)(h * S + q0 + wm + i * 16 + fm) * 256
                            + map * 128 + kb * 64 + ks * 32 + fq * 8;
                aR[ks][i] = *(const f16x8*)&qp_r[qa];
                aI[ks][i] = *(const f16x8*)&qp_i[qa];
            }
        __syncthreads();
        // complex QK^T: sr = qr.kr + qi.ki ; si = qi.kr - qr.ki
        #pragma unroll
        for (int ks = 0; ks < 2; ++ks) {
            f16x8 nR0 = fneg8(aR[ks][0]), nR1 = fneg8(aR[ks][1]);
            #pragma unroll
            for (int j = 0; j < 4; ++j) {
                int bo = (wn + j * 16 + fm) * 72 + ks * 32 + fq * 8;
                f16x8 bR = *(const f16x8*)&Kr[bo];
                f16x8 bI = *(const f16x8*)&Ki[bo];
                sr[0][j] = __builtin_amdgcn_mfma_f32_16x16x32_f16(aR[ks][0], bR, sr[0][j], 0, 0, 0);
                si[0][j] = __builtin_amdgcn_mfma_f32_16x16x32_f16(aI[ks][0], bR, si[0][j], 0, 0, 0);
                sr[0][j] = __builtin_amdgcn_mfma_f32_16x16x32_f16(aI[ks][0], bI, sr[0][j], 0, 0, 0);
                si[0][j] = __builtin_amdgcn_mfma_f32_16x16x32_f16(nR0, bI, si[0][j], 0, 0, 0);
                sr[1][j] = __builtin_amdgcn_mfma_f32_16x16x32_f16(aR[ks][1], bR, sr[1][j], 0, 0, 0);
                si[1][j] = __builtin_amdgcn_mfma_f32_16x16x32_f16(aI[ks][1], bR, si[1][j], 0, 0, 0);
                sr[1][j] = __builtin_amdgcn_mfma_f32_16x16x32_f16(aI[ks][1], bI, sr[1][j], 0, 0, 0);
                si[1][j] = __builtin_amdgcn_mfma_f32_16x16x32_f16(nR1, bI, si[1][j], 0, 0, 0);
            }
        }
    }
    const float scale = 0.08838834764831845f;
    #pragma unroll
    for (int i = 0; i < 2; ++i)
        #pragma unroll
        for (int j = 0; j < 4; ++j) {
            int kcol = c0 + wn + j * 16 + fm;
            #pragma unroll
            for (int reg = 0; reg < 4; ++reg) {
                int q = q0 + wm + i * 16 + fq * 4 + reg;
                float r1 = sr[i][j][reg], I1 = si[i][j][reg];
                float m1 = sqrtf(fmaf(r1, r1, fmaf(I1, I1, 1e-8f))) * scale;
                w16[(((size_t)hh * 2 + map) * S + q) * S + kcol] = f2h(m1);
            }
        }
}

// ============================================================
// Per-row softmax STATS only (read-only over mags): stats[row]=(max, 1/sum).
// (reverted to proven r1 kernel — separate parallel pass over L3-resident w16)
// ============================================================
__global__ __launch_bounds__(256) void smstats(const short* __restrict__ w16,
                                               float2* __restrict__ stats)
{
    const short* row = w16 + (size_t)blockIdx.x * S;
    int t = threadIdx.x;
    short4 s = ((const short4*)row)[t];
    float f0 = h2f(s.x), f1 = h2f(s.y), f2v = h2f(s.z), f3 = h2f(s.w);
    float m = fmaxf(fmaxf(f0, f1), fmaxf(f2v, f3));
    #pragma unroll
    for (int off = 32; off; off >>= 1) m = fmaxf(m, __shfl_xor(m, off));
    __shared__ float redm[4], reds[4];
    int w = t >> 6;
    if ((t & 63) == 0) redm[w] = m;
    __syncthreads();
    m = fmaxf(fmaxf(redm[0], redm[1]), fmaxf(redm[2], redm[3]));
    float ssum = __expf(f0 - m) + __expf(f1 - m) + __expf(f2v - m) + __expf(f3 - m);
    #pragma unroll
    for (int off = 32; off; off >>= 1) ssum += __shfl_xor(ssum, off);
    if ((t & 63) == 0) reds[w] = ssum;
    __syncthreads();
    if (t == 0) {
        float total = reds[0] + reds[1] + reds[2] + reds[3];
        stats[blockIdx.x] = make_float2(m, 1.0f / total);
    }
}

// ============================================================
// AV: 32q x full 128d, both maps, ONE complex comp per block (blockIdx.y).
// (reverted to proven r1 kernel — stats precomputed, staging is pure exp)
// ============================================================
__global__ __launch_bounds__(256) void av_mfma(
    const short* __restrict__ w16, const float2* __restrict__ stats,
    const short* __restrict__ vpT_r, const short* __restrict__ vpT_i,
    short* __restrict__ acat_r, short* __restrict__ acat_i, int h0)
{
    __shared__ short W1[32 * 72], W2[32 * 72], Vc[128 * 72];
    const int t = threadIdx.x;
    const int hh = blockIdx.z, h = h0 + hh;
    const int comp = blockIdx.y;
    const int q0 = blockIdx.x * 32;
    const short* vpT = comp ? vpT_i : vpT_r;
    short* acat = comp ? acat_i : acat_r;
    const float2* st1 = stats + ((size_t)hh * 2 + 0) * S;
    const float2* st2 = stats + ((size_t)hh * 2 + 1) * S;
    const int lane = t & 63, wid = t >> 6;
    const int wm = (wid >> 1) * 16, wn = (wid & 1) * 64;
    const int fm = lane & 15, fq = lane >> 4;
    f32x4 zero4 = {0.f, 0.f, 0.f, 0.f};
    f32x4 a1[4], a2[4];
    #pragma unroll
    for (int j = 0; j < 4; ++j) { a1[j] = zero4; a2[j] = zero4; }

    for (int k0 = 0; k0 < S; k0 += 64) {
        __syncthreads();
        #pragma unroll
        for (int it = 0; it < 2; ++it) {
            int lin = it * 256 + t;
            int r = lin >> 4, k4 = (lin & 15) * 4;
            float2 s1v = st1[q0 + r];
            float2 s2v = st2[q0 + r];
            short4 m1 = *(const short4*)&w16[(((size_t)hh * 2 + 0) * S + q0 + r) * S + k0 + k4];
            short4 m2 = *(const short4*)&w16[(((size_t)hh * 2 + 1) * S + q0 + r) * S + k0 + k4];
            *(short4*)&W1[r * 72 + k4] = make_short4(
                f2h(__expf(h2f(m1.x) - s1v.x) * s1v.y), f2h(__expf(h2f(m1.y) - s1v.x) * s1v.y),
                f2h(__expf(h2f(m1.z) - s1v.x) * s1v.y), f2h(__expf(h2f(m1.w) - s1v.x) * s1v.y));
            *(short4*)&W2[r * 72 + k4] = make_short4(
                f2h(__expf(h2f(m2.x) - s2v.x) * s2v.y), f2h(__expf(h2f(m2.y) - s2v.x) * s2v.y),
                f2h(__expf(h2f(m2.z) - s2v.x) * s2v.y), f2h(__expf(h2f(m2.w) - s2v.x) * s2v.y));
        }
        #pragma unroll
        for (int it = 0; it < 8; ++it) {
            int lin = it * 256 + t;
            int dd = lin >> 4, k4 = (lin & 15) * 4;
            *(short4*)&Vc[dd * 72 + k4] = *(const short4*)&vpT[(size_t)(h * 128 + dd) * 1024 + k0 + k4];
        }
        __syncthreads();
        #pragma unroll
        for (int ks = 0; ks < 64; ks += 32) {
            f16x8 b[4];
            #pragma unroll
            for (int j = 0; j < 4; ++j)
                b[j] = *(const f16x8*)&Vc[(wn + j * 16 + fm) * 72 + ks + fq * 8];
            int wo = (wm + fm) * 72 + ks + fq * 8;
            f16x8 w1f = *(const f16x8*)&W1[wo];
            f16x8 w2f = *(const f16x8*)&W2[wo];
            #pragma unroll
            for (int j = 0; j < 4; ++j) {
                a1[j] = __builtin_amdgcn_mfma_f32_16x16x32_f16(w1f, b[j], a1[j], 0, 0, 0);
                a2[j] = __builtin_amdgcn_mfma_f32_16x16x32_f16(w2f, b[j], a2[j], 0, 0, 0);
            }
        }
    }
    #pragma unroll
    for (int j = 0; j < 4; ++j) {
        int d = wn + j * 16 + fm;
        #pragma unroll
        for (int reg = 0; reg < 4; ++reg) {
            int q = q0 + wm + fq * 4 + reg;
            size_t rowb = (size_t)(h * S + q) * 256;
            acat[rowb + d]       = f2h(a1[j][reg]);
            acat[rowb + 128 + d] = f2h(a2[j][reg]);
        }
    }
}

// ============================================================
// RMS over 256 complex + sub_w + (a1 - lam*a2) + complex gate.
// (unchanged — proven r1 kernel)
// ============================================================
__global__ __launch_bounds__(256) void rmsgate_kernel(
    const short* __restrict__ acat_r, const short* __restrict__ acat_i,
    const float* __restrict__ sub_w, const float* __restrict__ lam_ptr,
    short* __restrict__ gp_r, short* __restrict__ gp_i)
{
    int row = blockIdx.x;
    int t = threadIdx.x;
    float ar = h2f(acat_r[(size_t)row * 256 + t]);
    float ai = h2f(acat_i[(size_t)row * 256 + t]);
    float ss = fmaf(ar, ar, ai * ai);
    #pragma unroll
    for (int off = 32; off; off >>= 1) ss += __shfl_xor(ss, off);
    __shared__ float red[4];
    if ((t & 63) == 0) red[t >> 6] = ss;
    __syncthreads();
    float total = red[0] + red[1] + red[2] + red[3];
    float inv_rms = 1.0f / sqrtf(total * (1.0f / 256.0f) + 1e-5f);
    float sw = sub_w[t];
    __shared__ float Cr[256], Ci[256];
    Cr[t] = ar * inv_rms * sw;
    Ci[t] = ai * inv_rms * sw;
    __syncthreads();
    if (t < 128) {
        float lam = lam_ptr[0];
        float o_r = Cr[t] - lam * Cr[t + 128];
        float o_i = Ci[t] - lam * Ci[t + 128];
        float gr = h2f(gp_r[(size_t)row * 128 + t]);
        float gi = h2f(gp_i[(size_t)row * 128 + t]);
        gp_r[(size_t)row * 128 + t] = f2h(gr * o_r - gi * o_i);
        gp_i[(size_t)row * 128 + t] = f2h(gr * o_i + gi * o_r);
    }
}

// ============================================================
extern "C" void kernel_launch(void* const* d_in, const int* in_sizes, int n_in,
                              void* d_out, int out_size, void* d_ws, size_t ws_size,
                              hipStream_t stream)
{
    (void)in_sizes; (void)n_in; (void)out_size;
    const float* q_r    = (const float*)d_in[0];
    const float* q_i    = (const float*)d_in[1];
    const float* k_r    = (const float*)d_in[2];
    const float* k_i    = (const float*)d_in[3];
    const float* v_r    = (const float*)d_in[4];
    const float* v_i    = (const float*)d_in[5];
    const float* pe_q_r = (const float*)d_in[6];
    const float* pe_q_i = (const float*)d_in[7];
    const float* pe_k_r = (const float*)d_in[8];
    const float* pe_k_i = (const float*)d_in[9];
    const float* qw_r   = (const float*)d_in[10];
    const float* qw_i   = (const float*)d_in[11];
    const float* qb_r   = (const float*)d_in[12];
    const float* qb_i   = (const float*)d_in[13];
    const float* kw_r   = (const float*)d_in[14];
    const float* kw_i   = (const float*)d_in[15];
    const float* kb_r   = (const float*)d_in[16];
    const float* kb_i   = (const float*)d_in[17];
    const float* vw_r   = (const float*)d_in[18];
    const float* vw_i   = (const float*)d_in[19];
    const float* vb_r   = (const float*)d_in[20];
    const float* vb_i   = (const float*)d_in[21];
    const float* gw_r   = (const float*)d_in[22];
    const float* gw_i   = (const float*)d_in[23];
    const float* gb_r   = (const float*)d_in[24];
    const float* gb_i   = (const float*)d_in[25];
    const float* ow_r   = (const float*)d_in[26];
    const float* ow_i   = (const float*)d_in[27];
    const float* ob_r   = (const float*)d_in[28];
    const float* ob_i   = (const float*)d_in[29];
    const float* lq1    = (const float*)d_in[30];
    const float* lk1    = (const float*)d_in[31];
    const float* lq2    = (const float*)d_in[32];
    const float* lk2    = (const float*)d_in[33];
    const float* sub_w  = (const float*)d_in[34];

    char* ws = (char*)d_ws;
    short* qp_r   = (short*)(ws + WS_QP_R);
    short* qp_i   = (short*)(ws + WS_QP_I);
    short* kp_r   = (short*)(ws + WS_KP_R);
    short* kp_i   = (short*)(ws + WS_KP_I);
    short* vpT_r  = (short*)(ws + WS_VPT_R);
    short* vpT_i  = (short*)(ws + WS_VPT_I);
    short* gp_r   = (short*)(ws + WS_GP_R);
    short* gp_i   = (short*)(ws + WS_GP_I);
    short* acat_r = (short*)(ws + WS_ACAT_R);
    short* acat_i = (short*)(ws + WS_ACAT_I);
    float* lam    = (float*)(ws + WS_LAM);
    short* w16    = (short*)(ws + WS_SC);

    float* out_r = (float*)d_out;
    float* out_i = out_r + (size_t)NROWS * D;

    // head-chunking by workspace (depends only on ws_size -> graph-safe)
    size_t avail = ws_size > WS_SC ? ws_size - WS_SC : 0;
    int nh_chunk = (int)(avail / (W16_PER_HEAD + STAT_PER_HEAD));
    if (nh_chunk < 1) nh_chunk = 1;
    if (nh_chunk > H) nh_chunk = H;
    float2* stats = (float2*)(ws + WS_SC + (size_t)nh_chunk * W16_PER_HEAD);

    lam_kernel<<<1, 128, 0, stream>>>(lq1, lk1, lq2, lk2, lam);

    // ALL projections in one dispatch (q/k -> fp16 +PE; v -> fp16 T; g -> fp16)
    proj_all<<<dim3(192, 10), 256, 0, stream>>>(
        q_r, q_i, k_r, k_i, v_r, v_i, pe_q_r, pe_q_i, pe_k_r, pe_k_i,
        qw_r, qw_i, qb_r, qb_i, kw_r, kw_i, kb_r, kb_i,
        vw_r, vw_i, vb_r, vb_i, gw_r, gw_i, gb_r, gb_i,
        qp_r, qp_i, kp_r, kp_i, vpT_r, vpT_i, gp_r, gp_i);

    for (int h0 = 0; h0 < H; h0 += nh_chunk) {
        int nhh = (H - h0 < nh_chunk) ? (H - h0) : nh_chunk;
        score_mfma<<<dim3(16, 8, nhh * 2), 256, 0, stream>>>(qp_r, qp_i, kp_r, kp_i, w16, h0);
        smstats<<<nhh * 2 * S, 256, 0, stream>>>(w16, stats);
        av_mfma<<<dim3(32, 2, nhh), 256, 0, stream>>>(w16, stats, vpT_r, vpT_i, acat_r, acat_i, h0);
    }

    rmsgate_kernel<<<NROWS, 256, 0, stream>>>(acat_r, acat_i, sub_w, lam, gp_r, gp_i);

    oproj_mfma<<<dim3(192, 2), 256, 0, stream>>>(gp_r, gp_i, ow_r, ow_i, ob_r, ob_i, out_r, out_i);
}

// Round 5
// 303.919 us; speedup vs baseline: 1.8928x; 1.0444x over previous
//
#include <hip/hip_runtime.h>
#include <math.h>

#define H 12
#define S 1024
#define D 128
#define NROWS (H * S) // 12288

typedef __attribute__((ext_vector_type(8))) _Float16 f16x8; // 8 fp16 in 4 VGPRs
typedef __attribute__((ext_vector_type(4))) float f32x4;
typedef __attribute__((ext_vector_type(4))) int i32x4;

__device__ __forceinline__ short f2h(float f) { // RNE float->fp16, bits as short
    _Float16 h = (_Float16)f;
    return __builtin_bit_cast(short, h);
}
__device__ __forceinline__ float h2f(short s) {
    return (float)__builtin_bit_cast(_Float16, s);
}
__device__ __forceinline__ f16x8 fneg8(f16x8 v) { // packed sign flip
    i32x4 u = __builtin_bit_cast(i32x4, v);
    u ^= (int)0x80008000;
    return __builtin_bit_cast(f16x8, u);
}

// ---- workspace layout (BYTE offsets) ----
// qp fp16 [12288][256] r/i ; kp fp16 [12288][128] r/i ; vpT fp16 [H][128][1024] r/i
// gp fp16 [12288][128] r/i ; acat fp16 [12288][256] r/i ; lam ;
// per chunk: w16 fp16 2*S*S / head ; stats float2 2*S / head ; partial float2 2*S*16 / head
#define WS_QP_R   0ULL
#define WS_QP_I   6291456ULL
#define WS_KP_R   12582912ULL
#define WS_KP_I   15728640ULL
#define WS_VPT_R  18874368ULL
#define WS_VPT_I  22020096ULL
#define WS_GP_R   25165824ULL
#define WS_GP_I   28311552ULL
#define WS_ACAT_R 31457280ULL
#define WS_ACAT_I 37748736ULL
#define WS_LAM    44040192ULL
#define WS_SC     44040448ULL
#define W16_PER_HEAD   4194304ULL // 2*1024*1024*2B
#define STAT_PER_HEAD  16384ULL   // 2*1024*8B
#define PART_PER_HEAD  262144ULL  // 2*1024*16*8B

// ============================================================
__global__ void lam_kernel(const float* __restrict__ lq1, const float* __restrict__ lk1,
                           const float* __restrict__ lq2, const float* __restrict__ lk2,
                           float* __restrict__ lam_out)
{
    int t = threadIdx.x; // 128 threads
    float p1 = lq1[t] * lk1[t];
    float p2 = lq2[t] * lk2[t];
    #pragma unroll
    for (int off = 32; off; off >>= 1) {
        p1 += __shfl_xor(p1, off);
        p2 += __shfl_xor(p2, off);
    }
    __shared__ float s1[2], s2[2];
    if ((t & 63) == 0) { s1[t >> 6] = p1; s2[t >> 6] = p2; }
    __syncthreads();
    if (t == 0) {
        float l1 = expf(s1[0] + s1[1]);
        float l2 = expf(s2[0] + s2[1]);
        float x = l1 - l2 + 0.3555090675909693f; // 0.8 - 0.6*exp(-0.3)
        lam_out[0] = 1.0f / (1.0f + expf(-x));
    }
}

// ============================================================
// ALL FOUR projections in ONE dispatch. grid = (192, 10), 64x64 tiles.
// (unchanged — proven r1 kernel)
// ============================================================
__global__ __launch_bounds__(256) void proj_all(
    const float* __restrict__ q_r, const float* __restrict__ q_i,
    const float* __restrict__ k_r, const float* __restrict__ k_i,
    const float* __restrict__ v_r, const float* __restrict__ v_i,
    const float* __restrict__ pe_q_r, const float* __restrict__ pe_q_i,
    const float* __restrict__ pe_k_r, const float* __restrict__ pe_k_i,
    const float* __restrict__ qw_r, const float* __restrict__ qw_i,
    const float* __restrict__ qb_r, const float* __restrict__ qb_i,
    const float* __restrict__ kw_r, const float* __restrict__ kw_i,
    const float* __restrict__ kb_r, const float* __restrict__ kb_i,
    const float* __restrict__ vw_r, const float* __restrict__ vw_i,
    const float* __restrict__ vb_r, const float* __restrict__ vb_i,
    const float* __restrict__ gw_r, const float* __restrict__ gw_i,
    const float* __restrict__ gb_r, const float* __restrict__ gb_i,
    short* __restrict__ qp_r, short* __restrict__ qp_i,
    short* __restrict__ kp_r, short* __restrict__ kp_i,
    short* __restrict__ vpT_r, short* __restrict__ vpT_i,
    short* __restrict__ gp_r, short* __restrict__ gp_i)
{
    const int y = blockIdx.y;
    const float *xr, *xi, *wr, *wi, *br, *bi, *per = nullptr, *pei = nullptr;
    short *outr_, *outi_;
    int M, omode, col0;
    if (y < 4)      { xr = q_r; xi = q_i; wr = qw_r; wi = qw_i; br = qb_r; bi = qb_i;
                      per = pe_q_r; pei = pe_q_i; outr_ = qp_r; outi_ = qp_i;
                      M = 256; omode = 1; col0 = y * 64; }
    else if (y < 6) { xr = k_r; xi = k_i; wr = kw_r; wi = kw_i; br = kb_r; bi = kb_i;
                      per = pe_k_r; pei = pe_k_i; outr_ = kp_r; outi_ = kp_i;
                      M = 128; omode = 1; col0 = (y - 4) * 64; }
    else if (y < 8) { xr = v_r; xi = v_i; wr = vw_r; wi = vw_i; br = vb_r; bi = vb_i;
                      outr_ = vpT_r; outi_ = vpT_i;
                      M = 128; omode = 2; col0 = (y - 6) * 64; }
    else            { xr = q_r; xi = q_i; wr = gw_r; wi = gw_i; br = gb_r; bi = gb_i;
                      outr_ = gp_r; outi_ = gp_i;
                      M = 128; omode = 1; col0 = (y - 8) * 64; }

    __shared__ short As[64 * 72], Brs[64 * 72], Bis[64 * 72];
    const int t = threadIdx.x;
    const int row0 = blockIdx.x * 64;
    const int lane = t & 63, wid = t >> 6;
    const int wm = (wid >> 1) * 32, wn = (wid & 1) * 32;
    const int fm = lane & 15, fq = lane >> 4;
    f32x4 zero4 = {0.f, 0.f, 0.f, 0.f};
    f32x4 accr[2][2], acci[2][2];
    #pragma unroll
    for (int i = 0; i < 2; ++i)
        #pragma unroll
        for (int j = 0; j < 2; ++j) { accr[i][j] = zero4; acci[i][j] = zero4; }

    for (int c = 0; c < 4; ++c) {
        const bool hi = (c >= 2);
        const int kb = (c & 1) * 64;
        const float* Asrc = hi ? xi : xr;
        const float* Brsrc = hi ? wi : wr;
        const float* Bisrc = hi ? wr : wi;
        const float bsign = hi ? -1.0f : 1.0f;
        __syncthreads();
        #pragma unroll
        for (int it = 0; it < 4; ++it) {
            int lin = it * 256 + t;
            int r = lin >> 4, k4 = (lin & 15) * 4;
            float4 va = *(const float4*)&Asrc[(size_t)(row0 + r) * 128 + kb + k4];
            *(short4*)&As[r * 72 + k4] = make_short4(f2h(va.x), f2h(va.y), f2h(va.z), f2h(va.w));
            float4 vr = *(const float4*)&Brsrc[(size_t)(col0 + r) * 128 + kb + k4];
            *(short4*)&Brs[r * 72 + k4] = make_short4(f2h(bsign * vr.x), f2h(bsign * vr.y),
                                                      f2h(bsign * vr.z), f2h(bsign * vr.w));
            float4 vi = *(const float4*)&Bisrc[(size_t)(col0 + r) * 128 + kb + k4];
            *(short4*)&Bis[r * 72 + k4] = make_short4(f2h(vi.x), f2h(vi.y), f2h(vi.z), f2h(vi.w));
        }
        __syncthreads();
        #pragma unroll
        for (int ks = 0; ks < 64; ks += 32) {
            f16x8 bfr[2], bfi[2];
            #pragma unroll
            for (int j = 0; j < 2; ++j) {
                bfr[j] = *(const f16x8*)&Brs[(wn + j * 16 + fm) * 72 + ks + fq * 8];
                bfi[j] = *(const f16x8*)&Bis[(wn + j * 16 + fm) * 72 + ks + fq * 8];
            }
            #pragma unroll
            for (int i = 0; i < 2; ++i) {
                f16x8 a = *(const f16x8*)&As[(wm + i * 16 + fm) * 72 + ks + fq * 8];
                #pragma unroll
                for (int j = 0; j < 2; ++j) {
                    accr[i][j] = __builtin_amdgcn_mfma_f32_16x16x32_f16(a, bfr[j], accr[i][j], 0, 0, 0);
                    acci[i][j] = __builtin_amdgcn_mfma_f32_16x16x32_f16(a, bfi[j], acci[i][j], 0, 0, 0);
                }
            }
        }
    }
    #pragma unroll
    for (int i = 0; i < 2; ++i)
        #pragma unroll
        for (int j = 0; j < 2; ++j) {
            int colc = col0 + wn + j * 16 + fm;
            float bbr = br[colc], bbi = bi[colc];
            if (omode == 2) {
                int rb = row0 + wm + i * 16 + fq * 4;
                int hq = rb >> 10, sq = rb & 1023;
                short4 o_r4 = make_short4(f2h(accr[i][j][0] + bbr), f2h(accr[i][j][1] + bbr),
                                          f2h(accr[i][j][2] + bbr), f2h(accr[i][j][3] + bbr));
                short4 o_i4 = make_short4(f2h(acci[i][j][0] + bbi), f2h(acci[i][j][1] + bbi),
                                          f2h(acci[i][j][2] + bbi), f2h(acci[i][j][3] + bbi));
                size_t ob = ((size_t)(hq * 128 + colc)) * 1024 + sq;
                *(short4*)&outr_[ob] = o_r4;
                *(short4*)&outi_[ob] = o_i4;
            } else {
                #pragma unroll
                for (int reg = 0; reg < 4; ++reg) {
                    int rr = row0 + wm + i * 16 + fq * 4 + reg;
                    float o_r = accr[i][j][reg] + bbr;
                    float o_i = acci[i][j][reg] + bbi;
                    if (per) {
                        o_r += per[(size_t)rr * 128 + (colc & 127)];
                        o_i += pei[(size_t)rr * 128 + (colc & 127)];
                    }
                    outr_[(size_t)rr * M + colc] = f2h(o_r);
                    outi_[(size_t)rr * M + colc] = f2h(o_i);
                }
            }
        }
}

// ============================================================
// o-projection: fp16 gated input gp, fp32 weights, fp32 out. 64x64 tiles.
// (unchanged — proven r1 kernel)
// ============================================================
__global__ __launch_bounds__(256) void oproj_mfma(
    const short* __restrict__ gp_r, const short* __restrict__ gp_i,
    const float* __restrict__ wr, const float* __restrict__ wi,
    const float* __restrict__ br, const float* __restrict__ bi,
    float* __restrict__ outr, float* __restrict__ outi)
{
    __shared__ short As[64 * 72], Brs[64 * 72], Bis[64 * 72];
    const int t = threadIdx.x;
    const int row0 = blockIdx.x * 64, col0 = blockIdx.y * 64;
    const int lane = t & 63, wid = t >> 6;
    const int wm = (wid >> 1) * 32, wn = (wid & 1) * 32;
    const int fm = lane & 15, fq = lane >> 4;
    f32x4 zero4 = {0.f, 0.f, 0.f, 0.f};
    f32x4 accr[2][2], acci[2][2];
    #pragma unroll
    for (int i = 0; i < 2; ++i)
        #pragma unroll
        for (int j = 0; j < 2; ++j) { accr[i][j] = zero4; acci[i][j] = zero4; }

    for (int c = 0; c < 4; ++c) {
        const bool hi = (c >= 2);
        const int kb = (c & 1) * 64;
        const short* Asrc = hi ? gp_i : gp_r;
        const float* Brsrc = hi ? wi : wr;
        const float* Bisrc = hi ? wr : wi;
        const float bsign = hi ? -1.0f : 1.0f;
        __syncthreads();
        #pragma unroll
        for (int it = 0; it < 4; ++it) {
            int lin = it * 256 + t;
            int r = lin >> 4, k4 = (lin & 15) * 4;
            *(short4*)&As[r * 72 + k4] = *(const short4*)&Asrc[(size_t)(row0 + r) * 128 + kb + k4];
            float4 vr = *(const float4*)&Brsrc[(size_t)(col0 + r) * 128 + kb + k4];
            *(short4*)&Brs[r * 72 + k4] = make_short4(f2h(bsign * vr.x), f2h(bsign * vr.y),
                                                      f2h(bsign * vr.z), f2h(bsign * vr.w));
            float4 vi = *(const float4*)&Bisrc[(size_t)(col0 + r) * 128 + kb + k4];
            *(short4*)&Bis[r * 72 + k4] = make_short4(f2h(vi.x), f2h(vi.y), f2h(vi.z), f2h(vi.w));
        }
        __syncthreads();
        #pragma unroll
        for (int ks = 0; ks < 64; ks += 32) {
            f16x8 bfr[2], bfi[2];
            #pragma unroll
            for (int j = 0; j < 2; ++j) {
                bfr[j] = *(const f16x8*)&Brs[(wn + j * 16 + fm) * 72 + ks + fq * 8];
                bfi[j] = *(const f16x8*)&Bis[(wn + j * 16 + fm) * 72 + ks + fq * 8];
            }
            #pragma unroll
            for (int i = 0; i < 2; ++i) {
                f16x8 a = *(const f16x8*)&As[(wm + i * 16 + fm) * 72 + ks + fq * 8];
                #pragma unroll
                for (int j = 0; j < 2; ++j) {
                    accr[i][j] = __builtin_amdgcn_mfma_f32_16x16x32_f16(a, bfr[j], accr[i][j], 0, 0, 0);
                    acci[i][j] = __builtin_amdgcn_mfma_f32_16x16x32_f16(a, bfi[j], acci[i][j], 0, 0, 0);
                }
            }
        }
    }
    #pragma unroll
    for (int i = 0; i < 2; ++i)
        #pragma unroll
        for (int j = 0; j < 2; ++j) {
            int colc = col0 + wn + j * 16 + fm;
            float bbr = br[colc], bbi = bi[colc];
            #pragma unroll
            for (int reg = 0; reg < 4; ++reg) {
                int rr = row0 + wm + i * 16 + fq * 4 + reg;
                outr[(size_t)rr * 128 + colc] = accr[i][j][reg] + bbr;
                outi[(size_t)rr * 128 + colc] = acci[i][j][reg] + bbi;
            }
        }
}

// ============================================================
// Scores (r1-proven structure): 64q x 128k tile, K-chunk 64, Q+Kt LDS-staged.
// NEW: epilogue also emits per-row PARTIAL softmax stats (max, sum of exp)
// over this block's 128 cols (one float2 per (row, c0, wn-half)) — computed
// from f32 mags via 16-lane shfl reduce, off the MFMA loop path, no barriers.
// ============================================================
__global__ __launch_bounds__(256) void score_mfma(
    const short* __restrict__ qp_r, const short* __restrict__ qp_i,
    const short* __restrict__ kp_r, const short* __restrict__ kp_i,
    short* __restrict__ w16, float2* __restrict__ partial, int h0)
{
    __shared__ short Qr[64 * 72], Qi[64 * 72], Kt[128 * 72];
    const int t = threadIdx.x;
    const int hh = blockIdx.z >> 1, map = blockIdx.z & 1;
    const int h = h0 + hh;
    const int q0 = blockIdx.x * 64, c0 = blockIdx.y * 128;
    const int lane = t & 63, wid = t >> 6;
    const int wm = (wid >> 1) * 32, wn = (wid & 1) * 64;
    const int fm = lane & 15, fq = lane >> 4;
    f32x4 zero4 = {0.f, 0.f, 0.f, 0.f};
    f32x4 sr[2][4], si[2][4];
    #pragma unroll
    for (int i = 0; i < 2; ++i)
        #pragma unroll
        for (int j = 0; j < 4; ++j) { sr[i][j] = zero4; si[i][j] = zero4; }

    for (int kb = 0; kb < 2; ++kb) {
        const int kbase = map * 128 + kb * 64;
        __syncthreads();
        #pragma unroll
        for (int i = 0; i < 4; ++i) {
            int lin = i * 256 + t;
            int r = lin >> 4, k4 = (lin & 15) * 4;
            size_t qb = (size_t)(h * S + q0 + r) * 256 + kbase + k4;
            *(short4*)&Qr[r * 72 + k4] = *(const short4*)&qp_r[qb];
            *(short4*)&Qi[r * 72 + k4] = *(const short4*)&qp_i[qb];
        }
        #pragma unroll
        for (int i = 0; i < 8; ++i) {
            int lin = i * 256 + t;
            int r = lin >> 4, k4 = (lin & 15) * 4;
            *(short4*)&Kt[r * 72 + k4] =
                *(const short4*)&kp_r[(size_t)(h * S + c0 + r) * 128 + kb * 64 + k4];
        }
        __syncthreads();
        f16x8 aR[2][2], aI[2][2]; // [ks][i]
        #pragma unroll
        for (int ks = 0; ks < 2; ++ks)
            #pragma unroll
            for (int i = 0; i < 2; ++i) {
                int ao = (wm + i * 16 + fm) * 72 + ks * 32 + fq * 8;
                aR[ks][i] = *(const f16x8*)&Qr[ao];
                aI[ks][i] = *(const f16x8*)&Qi[ao];
            }
        #pragma unroll
        for (int ks = 0; ks < 2; ++ks) {
            f16x8 b[4];
            #pragma unroll
            for (int j = 0; j < 4; ++j)
                b[j] = *(const f16x8*)&Kt[(wn + j * 16 + fm) * 72 + ks * 32 + fq * 8];
            #pragma unroll
            for (int i = 0; i < 2; ++i)
                #pragma unroll
                for (int j = 0; j < 4; ++j) {
                    sr[i][j] = __builtin_amdgcn_mfma_f32_16x16x32_f16(aR[ks][i], b[j], sr[i][j], 0, 0, 0);
                    si[i][j] = __builtin_amdgcn_mfma_f32_16x16x32_f16(aI[ks][i], b[j], si[i][j], 0, 0, 0);
                }
        }
        __syncthreads();
        #pragma unroll
        for (int i = 0; i < 8; ++i) {
            int lin = i * 256 + t;
            int r = lin >> 4, k4 = (lin & 15) * 4;
            *(short4*)&Kt[r * 72 + k4] =
                *(const short4*)&kp_i[(size_t)(h * S + c0 + r) * 128 + kb * 64 + k4];
        }
        __syncthreads();
        #pragma unroll
        for (int ks = 0; ks < 2; ++ks) {
            f16x8 b[4];
            #pragma unroll
            for (int j = 0; j < 4; ++j)
                b[j] = *(const f16x8*)&Kt[(wn + j * 16 + fm) * 72 + ks * 32 + fq * 8];
            f16x8 nR0 = fneg8(aR[ks][0]), nR1 = fneg8(aR[ks][1]);
            #pragma unroll
            for (int j = 0; j < 4; ++j) {
                sr[0][j] = __builtin_amdgcn_mfma_f32_16x16x32_f16(aI[ks][0], b[j], sr[0][j], 0, 0, 0);
                si[0][j] = __builtin_amdgcn_mfma_f32_16x16x32_f16(nR0, b[j], si[0][j], 0, 0, 0);
                sr[1][j] = __builtin_amdgcn_mfma_f32_16x16x32_f16(aI[ks][1], b[j], sr[1][j], 0, 0, 0);
                si[1][j] = __builtin_amdgcn_mfma_f32_16x16x32_f16(nR1, b[j], si[1][j], 0, 0, 0);
            }
        }
    }
    const float scale = 0.08838834764831845f;
    // mags -> w16 (fp16), keep f32 mags in sr for the stats reduce
    #pragma unroll
    for (int i = 0; i < 2; ++i)
        #pragma unroll
        for (int j = 0; j < 4; ++j) {
            int kcol = c0 + wn + j * 16 + fm;
            #pragma unroll
            for (int reg = 0; reg < 4; ++reg) {
                int q = q0 + wm + i * 16 + fq * 4 + reg;
                float r1 = sr[i][j][reg], I1 = si[i][j][reg];
                float m1 = sqrtf(fmaf(r1, r1, fmaf(I1, I1, 1e-8f))) * scale;
                sr[i][j][reg] = m1;
                w16[(((size_t)hh * 2 + map) * S + q) * S + kcol] = f2h(m1);
            }
        }
    // per-row partial (max, sum(exp(x-max))) over this wave's 64 cols.
    // Rows: 4 fq-groups reduce in parallel; shfl_xor off<16 stays in-group.
    #pragma unroll
    for (int i = 0; i < 2; ++i)
        #pragma unroll
        for (int reg = 0; reg < 4; ++reg) {
            float mx = fmaxf(fmaxf(sr[i][0][reg], sr[i][1][reg]),
                             fmaxf(sr[i][2][reg], sr[i][3][reg]));
            #pragma unroll
            for (int off = 1; off < 16; off <<= 1) mx = fmaxf(mx, __shfl_xor(mx, off));
            float sm = __expf(sr[i][0][reg] - mx) + __expf(sr[i][1][reg] - mx)
                     + __expf(sr[i][2][reg] - mx) + __expf(sr[i][3][reg] - mx);
            #pragma unroll
            for (int off = 1; off < 16; off <<= 1) sm += __shfl_xor(sm, off);
            if (fm == 0) {
                int q = q0 + wm + i * 16 + fq * 4 + reg;
                size_t prow = ((size_t)hh * 2 + map) * S + q;
                partial[prow * 16 + blockIdx.y * 2 + (wn >> 6)] = make_float2(mx, sm);
            }
        }
}

// ============================================================
// Combine 16 per-block partials per row into stats[row] = (max, 1/sum).
// Replaces the smstats full 50MB re-read. One thread per row.
// ============================================================
__global__ __launch_bounds__(256) void smcombine(const float2* __restrict__ partial,
                                                 float2* __restrict__ stats)
{
    int row = blockIdx.x * 256 + threadIdx.x;
    const float2* p = partial + (size_t)row * 16;
    float2 p0 = p[0];
    float m = p0.x;
    #pragma unroll
    for (int b = 1; b < 16; ++b) m = fmaxf(m, p[b].x);
    float l = 0.f;
    #pragma unroll
    for (int b = 0; b < 16; ++b) l += p[b].y * __expf(p[b].x - m);
    stats[row] = make_float2(m, 1.0f / l);
}

// ============================================================
// AV: 32q x full 128d, both maps, ONE complex comp per block (blockIdx.y).
// (unchanged — proven r1 kernel; consumes stats as before)
// ============================================================
__global__ __launch_bounds__(256) void av_mfma(
    const short* __restrict__ w16, const float2* __restrict__ stats,
    const short* __restrict__ vpT_r, const short* __restrict__ vpT_i,
    short* __restrict__ acat_r, short* __restrict__ acat_i, int h0)
{
    __shared__ short W1[32 * 72], W2[32 * 72], Vc[128 * 72];
    const int t = threadIdx.x;
    const int hh = blockIdx.z, h = h0 + hh;
    const int comp = blockIdx.y;
    const int q0 = blockIdx.x * 32;
    const short* vpT = comp ? vpT_i : vpT_r;
    short* acat = comp ? acat_i : acat_r;
    const float2* st1 = stats + ((size_t)hh * 2 + 0) * S;
    const float2* st2 = stats + ((size_t)hh * 2 + 1) * S;
    const int lane = t & 63, wid = t >> 6;
    const int wm = (wid >> 1) * 16, wn = (wid & 1) * 64;
    const int fm = lane & 15, fq = lane >> 4;
    f32x4 zero4 = {0.f, 0.f, 0.f, 0.f};
    f32x4 a1[4], a2[4];
    #pragma unroll
    for (int j = 0; j < 4; ++j) { a1[j] = zero4; a2[j] = zero4; }

    for (int k0 = 0; k0 < S; k0 += 64) {
        __syncthreads();
        #pragma unroll
        for (int it = 0; it < 2; ++it) {
            int lin = it * 256 + t;
            int r = lin >> 4, k4 = (lin & 15) * 4;
            float2 s1v = st1[q0 + r];
            float2 s2v = st2[q0 + r];
            short4 m1 = *(const short4*)&w16[(((size_t)hh * 2 + 0) * S + q0 + r) * S + k0 + k4];
            short4 m2 = *(const short4*)&w16[(((size_t)hh * 2 + 1) * S + q0 + r) * S + k0 + k4];
            *(short4*)&W1[r * 72 + k4] = make_short4(
                f2h(__expf(h2f(m1.x) - s1v.x) * s1v.y), f2h(__expf(h2f(m1.y) - s1v.x) * s1v.y),
                f2h(__expf(h2f(m1.z) - s1v.x) * s1v.y), f2h(__expf(h2f(m1.w) - s1v.x) * s1v.y));
            *(short4*)&W2[r * 72 + k4] = make_short4(
                f2h(__expf(h2f(m2.x) - s2v.x) * s2v.y), f2h(__expf(h2f(m2.y) - s2v.x) * s2v.y),
                f2h(__expf(h2f(m2.z) - s2v.x) * s2v.y), f2h(__expf(h2f(m2.w) - s2v.x) * s2v.y));
        }
        #pragma unroll
        for (int it = 0; it < 8; ++it) {
            int lin = it * 256 + t;
            int dd = lin >> 4, k4 = (lin & 15) * 4;
            *(short4*)&Vc[dd * 72 + k4] = *(const short4*)&vpT[(size_t)(h * 128 + dd) * 1024 + k0 + k4];
        }
        __syncthreads();
        #pragma unroll
        for (int ks = 0; ks < 64; ks += 32) {
            f16x8 b[4];
            #pragma unroll
            for (int j = 0; j < 4; ++j)
                b[j] = *(const f16x8*)&Vc[(wn + j * 16 + fm) * 72 + ks + fq * 8];
            int wo = (wm + fm) * 72 + ks + fq * 8;
            f16x8 w1f = *(const f16x8*)&W1[wo];
            f16x8 w2f = *(const f16x8*)&W2[wo];
            #pragma unroll
            for (int j = 0; j < 4; ++j) {
                a1[j] = __builtin_amdgcn_mfma_f32_16x16x32_f16(w1f, b[j], a1[j], 0, 0, 0);
                a2[j] = __builtin_amdgcn_mfma_f32_16x16x32_f16(w2f, b[j], a2[j], 0, 0, 0);
            }
        }
    }
    #pragma unroll
    for (int j = 0; j < 4; ++j) {
        int d = wn + j * 16 + fm;
        #pragma unroll
        for (int reg = 0; reg < 4; ++reg) {
            int q = q0 + wm + fq * 4 + reg;
            size_t rowb = (size_t)(h * S + q) * 256;
            acat[rowb + d]       = f2h(a1[j][reg]);
            acat[rowb + 128 + d] = f2h(a2[j][reg]);
        }
    }
}

// ============================================================
// RMS over 256 complex + sub_w + (a1 - lam*a2) + complex gate.
// (unchanged — proven r1 kernel)
// ============================================================
__global__ __launch_bounds__(256) void rmsgate_kernel(
    const short* __restrict__ acat_r, const short* __restrict__ acat_i,
    const float* __restrict__ sub_w, const float* __restrict__ lam_ptr,
    short* __restrict__ gp_r, short* __restrict__ gp_i)
{
    int row = blockIdx.x;
    int t = threadIdx.x;
    float ar = h2f(acat_r[(size_t)row * 256 + t]);
    float ai = h2f(acat_i[(size_t)row * 256 + t]);
    float ss = fmaf(ar, ar, ai * ai);
    #pragma unroll
    for (int off = 32; off; off >>= 1) ss += __shfl_xor(ss, off);
    __shared__ float red[4];
    if ((t & 63) == 0) red[t >> 6] = ss;
    __syncthreads();
    float total = red[0] + red[1] + red[2] + red[3];
    float inv_rms = 1.0f / sqrtf(total * (1.0f / 256.0f) + 1e-5f);
    float sw = sub_w[t];
    __shared__ float Cr[256], Ci[256];
    Cr[t] = ar * inv_rms * sw;
    Ci[t] = ai * inv_rms * sw;
    __syncthreads();
    if (t < 128) {
        float lam = lam_ptr[0];
        float o_r = Cr[t] - lam * Cr[t + 128];
        float o_i = Ci[t] - lam * Ci[t + 128];
        float gr = h2f(gp_r[(size_t)row * 128 + t]);
        float gi = h2f(gp_i[(size_t)row * 128 + t]);
        gp_r[(size_t)row * 128 + t] = f2h(gr * o_r - gi * o_i);
        gp_i[(size_t)row * 128 + t] = f2h(gr * o_i + gi * o_r);
    }
}

// ============================================================
extern "C" void kernel_launch(void* const* d_in, const int* in_sizes, int n_in,
                              void* d_out, int out_size, void* d_ws, size_t ws_size,
                              hipStream_t stream)
{
    (void)in_sizes; (void)n_in; (void)out_size;
    const float* q_r    = (const float*)d_in[0];
    const float* q_i    = (const float*)d_in[1];
    const float* k_r    = (const float*)d_in[2];
    const float* k_i    = (const float*)d_in[3];
    const float* v_r    = (const float*)d_in[4];
    const float* v_i    = (const float*)d_in[5];
    const float* pe_q_r = (const float*)d_in[6];
    const float* pe_q_i = (const float*)d_in[7];
    const float* pe_k_r = (const float*)d_in[8];
    const float* pe_k_i = (const float*)d_in[9];
    const float* qw_r   = (const float*)d_in[10];
    const float* qw_i   = (const float*)d_in[11];
    const float* qb_r   = (const float*)d_in[12];
    const float* qb_i   = (const float*)d_in[13];
    const float* kw_r   = (const float*)d_in[14];
    const float* kw_i   = (const float*)d_in[15];
    const float* kb_r   = (const float*)d_in[16];
    const float* kb_i   = (const float*)d_in[17];
    const float* vw_r   = (const float*)d_in[18];
    const float* vw_i   = (const float*)d_in[19];
    const float* vb_r   = (const float*)d_in[20];
    const float* vb_i   = (const float*)d_in[21];
    const float* gw_r   = (const float*)d_in[22];
    const float* gw_i   = (const float*)d_in[23];
    const float* gb_r   = (const float*)d_in[24];
    const float* gb_i   = (const float*)d_in[25];
    const float* ow_r   = (const float*)d_in[26];
    const float* ow_i   = (const float*)d_in[27];
    const float* ob_r   = (const float*)d_in[28];
    const float* ob_i   = (const float*)d_in[29];
    const float* lq1    = (const float*)d_in[30];
    const float* lk1    = (const float*)d_in[31];
    const float* lq2    = (const float*)d_in[32];
    const float* lk2    = (const float*)d_in[33];
    const float* sub_w  = (const float*)d_in[34];

    char* ws = (char*)d_ws;
    short* qp_r   = (short*)(ws + WS_QP_R);
    short* qp_i   = (short*)(ws + WS_QP_I);
    short* kp_r   = (short*)(ws + WS_KP_R);
    short* kp_i   = (short*)(ws + WS_KP_I);
    short* vpT_r  = (short*)(ws + WS_VPT_R);
    short* vpT_i  = (short*)(ws + WS_VPT_I);
    short* gp_r   = (short*)(ws + WS_GP_R);
    short* gp_i   = (short*)(ws + WS_GP_I);
    short* acat_r = (short*)(ws + WS_ACAT_R);
    short* acat_i = (short*)(ws + WS_ACAT_I);
    float* lam    = (float*)(ws + WS_LAM);
    short* w16    = (short*)(ws + WS_SC);

    float* out_r = (float*)d_out;
    float* out_i = out_r + (size_t)NROWS * D;

    // head-chunking by workspace (depends only on ws_size -> graph-safe)
    size_t avail = ws_size > WS_SC ? ws_size - WS_SC : 0;
    int nh_chunk = (int)(avail / (W16_PER_HEAD + STAT_PER_HEAD + PART_PER_HEAD));
    if (nh_chunk < 1) nh_chunk = 1;
    if (nh_chunk > H) nh_chunk = H;
    float2* stats   = (float2*)(ws + WS_SC + (size_t)nh_chunk * W16_PER_HEAD);
    float2* partial = (float2*)(ws + WS_SC + (size_t)nh_chunk * (W16_PER_HEAD + STAT_PER_HEAD));

    lam_kernel<<<1, 128, 0, stream>>>(lq1, lk1, lq2, lk2, lam);

    // ALL projections in one dispatch (q/k -> fp16 +PE; v -> fp16 T; g -> fp16)
    proj_all<<<dim3(192, 10), 256, 0, stream>>>(
        q_r, q_i, k_r, k_i, v_r, v_i, pe_q_r, pe_q_i, pe_k_r, pe_k_i,
        qw_r, qw_i, qb_r, qb_i, kw_r, kw_i, kb_r, kb_i,
        vw_r, vw_i, vb_r, vb_i, gw_r, gw_i, gb_r, gb_i,
        qp_r, qp_i, kp_r, kp_i, vpT_r, vpT_i, gp_r, gp_i);

    for (int h0 = 0; h0 < H; h0 += nh_chunk) {
        int nhh = (H - h0 < nh_chunk) ? (H - h0) : nh_chunk;
        score_mfma<<<dim3(16, 8, nhh * 2), 256, 0, stream>>>(qp_r, qp_i, kp_r, kp_i, w16, partial, h0);
        smcombine<<<nhh * 8, 256, 0, stream>>>(partial, stats);
        av_mfma<<<dim3(32, 2, nhh), 256, 0, stream>>>(w16, stats, vpT_r, vpT_i, acat_r, acat_i, h0);
    }

    rmsgate_kernel<<<NROWS, 256, 0, stream>>>(acat_r, acat_i, sub_w, lam, gp_r, gp_i);

    oproj_mfma<<<dim3(192, 2), 256, 0, stream>>>(gp_r, gp_i, ow_r, ow_i, ob_r, ob_i, out_r, out_i);
}

// Round 6
// 302.560 us; speedup vs baseline: 1.9013x; 1.0045x over previous
//
#include <hip/hip_runtime.h>
#include <math.h>

#define H 12
#define S 1024
#define D 128
#define NROWS (H * S) // 12288

typedef __attribute__((ext_vector_type(8))) _Float16 f16x8; // 8 fp16 in 4 VGPRs
typedef __attribute__((ext_vector_type(4))) float f32x4;
typedef __attribute__((ext_vector_type(4))) int i32x4;

__device__ __forceinline__ short f2h(float f) { // RNE float->fp16, bits as short
    _Float16 h = (_Float16)f;
    return __builtin_bit_cast(short, h);
}
__device__ __forceinline__ float h2f(short s) {
    return (float)__builtin_bit_cast(_Float16, s);
}
__device__ __forceinline__ f16x8 fneg8(f16x8 v) { // packed sign flip
    i32x4 u = __builtin_bit_cast(i32x4, v);
    u ^= (int)0x80008000;
    return __builtin_bit_cast(f16x8, u);
}

// ---- workspace layout (BYTE offsets) ----
// qp fp16 [12288][256] r/i ; kp fp16 [12288][128] r/i ; vpT fp16 [H][128][1024] r/i
// gp fp16 [12288][128] r/i ; acat fp16 [12288][256] r/i ; lam ;
// w16 region (per chunk-head 2*S*S fp16 + stats): ALSO reused transiently
// BEFORE score as { xh: 6 fp16 input copies ; wh: 8 fp16 proj weights }.
#define WS_QP_R   0ULL
#define WS_QP_I   6291456ULL
#define WS_KP_R   12582912ULL
#define WS_KP_I   15728640ULL
#define WS_VPT_R  18874368ULL
#define WS_VPT_I  22020096ULL
#define WS_GP_R   25165824ULL
#define WS_GP_I   28311552ULL
#define WS_ACAT_R 31457280ULL
#define WS_ACAT_I 37748736ULL
#define WS_LAM    44040192ULL
#define WS_SC     44040448ULL
#define W16_PER_HEAD   4194304ULL // 2*1024*1024*2B
#define STAT_PER_HEAD  16384ULL   // 2*1024*8B
#define XH_ELEMS  1572864         // elems per big tensor (12288*128)
#define WH_OFF_B  18874368ULL     // byte offset of wh inside w16 region (after 6 xh)

// ============================================================
__global__ void lam_kernel(const float* __restrict__ lq1, const float* __restrict__ lk1,
                           const float* __restrict__ lq2, const float* __restrict__ lk2,
                           float* __restrict__ lam_out)
{
    int t = threadIdx.x; // 128 threads
    float p1 = lq1[t] * lk1[t];
    float p2 = lq2[t] * lk2[t];
    #pragma unroll
    for (int off = 32; off; off >>= 1) {
        p1 += __shfl_xor(p1, off);
        p2 += __shfl_xor(p2, off);
    }
    __shared__ float s1[2], s2[2];
    if ((t & 63) == 0) { s1[t >> 6] = p1; s2[t >> 6] = p2; }
    __syncthreads();
    if (t == 0) {
        float l1 = expf(s1[0] + s1[1]);
        float l2 = expf(s2[0] + s2[1]);
        float x = l1 - l2 + 0.3555090675909693f; // 0.8 - 0.6*exp(-0.3)
        lam_out[0] = 1.0f / (1.0f + expf(-x));
    }
}

// ============================================================
// Pre-convert the 6 big f32 inputs to fp16 ONCE (kills per-block f2h in proj).
// grid (768, 6): 8 elems/thread. BW-bound: ~38MB read + 19MB write.
// ============================================================
__global__ __launch_bounds__(256) void cvt_inputs(
    const float* __restrict__ q_r, const float* __restrict__ q_i,
    const float* __restrict__ k_r, const float* __restrict__ k_i,
    const float* __restrict__ v_r, const float* __restrict__ v_i,
    short* __restrict__ xh)
{
    const float* srcs[6] = {q_r, q_i, k_r, k_i, v_r, v_i};
    const float* src = srcs[blockIdx.y];
    short* dst = xh + (size_t)blockIdx.y * XH_ELEMS;
    int base = (blockIdx.x * 256 + threadIdx.x) * 8;
    float4 a = *(const float4*)&src[base];
    float4 b = *(const float4*)&src[base + 4];
    short out[8] = {f2h(a.x), f2h(a.y), f2h(a.z), f2h(a.w),
                    f2h(b.x), f2h(b.y), f2h(b.z), f2h(b.w)};
    *(i32x4*)&dst[base] = *(i32x4*)out;
}

// ============================================================
// Pre-convert the 8 proj weight matrices to fp16. grid (16, 8), guarded.
// wh layout (shorts): qw_r 0, qw_i 32768, kw_r 65536, kw_i 81920,
//                     vw_r 98304, vw_i 114688, gw_r 131072, gw_i 147456
// ============================================================
__global__ __launch_bounds__(256) void cvt_weights(
    const float* __restrict__ qw_r, const float* __restrict__ qw_i,
    const float* __restrict__ kw_r, const float* __restrict__ kw_i,
    const float* __restrict__ vw_r, const float* __restrict__ vw_i,
    const float* __restrict__ gw_r, const float* __restrict__ gw_i,
    short* __restrict__ wh)
{
    const float* srcs[8] = {qw_r, qw_i, kw_r, kw_i, vw_r, vw_i, gw_r, gw_i};
    const int sizes[8] = {32768, 32768, 16384, 16384, 16384, 16384, 16384, 16384};
    const int offs[8]  = {0, 32768, 65536, 81920, 98304, 114688, 131072, 147456};
    int y = blockIdx.y;
    int base = (blockIdx.x * 256 + threadIdx.x) * 8;
    if (base < sizes[y]) {
        const float* src = srcs[y];
        short* dst = wh + offs[y];
        float4 a = *(const float4*)&src[base];
        float4 b = *(const float4*)&src[base + 4];
        short out[8] = {f2h(a.x), f2h(a.y), f2h(a.z), f2h(a.w),
                        f2h(b.x), f2h(b.y), f2h(b.z), f2h(b.w)};
        *(i32x4*)&dst[base] = *(i32x4*)out;
    }
}

// ============================================================
// ALL FOUR projections, fp16 sources: staging is pure 16B copies
// (6x fewer staging instructions than the f32+f2h version).
// grid = (192, 10), 64x64 tiles; MFMA loop and epilogue unchanged from r1.
// ============================================================
__global__ __launch_bounds__(256) void proj_all(
    const short* __restrict__ xh, const short* __restrict__ wh,
    const float* __restrict__ pe_q_r, const float* __restrict__ pe_q_i,
    const float* __restrict__ pe_k_r, const float* __restrict__ pe_k_i,
    const float* __restrict__ qb_r, const float* __restrict__ qb_i,
    const float* __restrict__ kb_r, const float* __restrict__ kb_i,
    const float* __restrict__ vb_r, const float* __restrict__ vb_i,
    const float* __restrict__ gb_r, const float* __restrict__ gb_i,
    short* __restrict__ qp_r, short* __restrict__ qp_i,
    short* __restrict__ kp_r, short* __restrict__ kp_i,
    short* __restrict__ vpT_r, short* __restrict__ vpT_i,
    short* __restrict__ gp_r, short* __restrict__ gp_i)
{
    const int y = blockIdx.y;
    const short *Xr, *Xi, *Wr, *Wi;
    const float *br, *bi, *per = nullptr, *pei = nullptr;
    short *outr_, *outi_;
    int M, omode, col0;
    if (y < 4)      { Xr = xh;                 Xi = xh + 1 * XH_ELEMS;
                      Wr = wh;                 Wi = wh + 32768;
                      br = qb_r; bi = qb_i; per = pe_q_r; pei = pe_q_i;
                      outr_ = qp_r; outi_ = qp_i; M = 256; omode = 1; col0 = y * 64; }
    else if (y < 6) { Xr = xh + 2 * XH_ELEMS;  Xi = xh + 3 * XH_ELEMS;
                      Wr = wh + 65536;         Wi = wh + 81920;
                      br = kb_r; bi = kb_i; per = pe_k_r; pei = pe_k_i;
                      outr_ = kp_r; outi_ = kp_i; M = 128; omode = 1; col0 = (y - 4) * 64; }
    else if (y < 8) { Xr = xh + 4 * XH_ELEMS;  Xi = xh + 5 * XH_ELEMS;
                      Wr = wh + 98304;         Wi = wh + 114688;
                      br = vb_r; bi = vb_i;
                      outr_ = vpT_r; outi_ = vpT_i; M = 128; omode = 2; col0 = (y - 6) * 64; }
    else            { Xr = xh;                 Xi = xh + 1 * XH_ELEMS;
                      Wr = wh + 131072;        Wi = wh + 147456;
                      br = gb_r; bi = gb_i;
                      outr_ = gp_r; outi_ = gp_i; M = 128; omode = 1; col0 = (y - 8) * 64; }

    __shared__ short As[64 * 72], Brs[64 * 72], Bis[64 * 72];
    const int t = threadIdx.x;
    const int row0 = blockIdx.x * 64;
    const int lane = t & 63, wid = t >> 6;
    const int wm = (wid >> 1) * 32, wn = (wid & 1) * 32;
    const int fm = lane & 15, fq = lane >> 4;
    f32x4 zero4 = {0.f, 0.f, 0.f, 0.f};
    f32x4 accr[2][2], acci[2][2];
    #pragma unroll
    for (int i = 0; i < 2; ++i)
        #pragma unroll
        for (int j = 0; j < 2; ++j) { accr[i][j] = zero4; acci[i][j] = zero4; }

    for (int c = 0; c < 4; ++c) {
        const bool hi = (c >= 2);
        const int kb = (c & 1) * 64;
        const short* Asrc = hi ? Xi : Xr;
        const short* Brsrc = hi ? Wi : Wr;
        const short* Bisrc = hi ? Wr : Wi;
        __syncthreads();
        #pragma unroll
        for (int it = 0; it < 2; ++it) {
            int lin = it * 256 + t;
            int r = lin >> 3, c8 = (lin & 7) * 8; // 64 rows x 64 cols, 8 elems/unit
            i32x4 va = *(const i32x4*)&Asrc[(size_t)(row0 + r) * 128 + kb + c8];
            *(i32x4*)&As[r * 72 + c8] = va;
            i32x4 vr = *(const i32x4*)&Brsrc[(size_t)(col0 + r) * 128 + kb + c8];
            if (hi) vr ^= (int)0x80008000; // bsign = -1 on wi-half
            *(i32x4*)&Brs[r * 72 + c8] = vr;
            i32x4 vi = *(const i32x4*)&Bisrc[(size_t)(col0 + r) * 128 + kb + c8];
            *(i32x4*)&Bis[r * 72 + c8] = vi;
        }
        __syncthreads();
        #pragma unroll
        for (int ks = 0; ks < 64; ks += 32) {
            f16x8 bfr[2], bfi[2];
            #pragma unroll
            for (int j = 0; j < 2; ++j) {
                bfr[j] = *(const f16x8*)&Brs[(wn + j * 16 + fm) * 72 + ks + fq * 8];
                bfi[j] = *(const f16x8*)&Bis[(wn + j * 16 + fm) * 72 + ks + fq * 8];
            }
            #pragma unroll
            for (int i = 0; i < 2; ++i) {
                f16x8 a = *(const f16x8*)&As[(wm + i * 16 + fm) * 72 + ks + fq * 8];
                #pragma unroll
                for (int j = 0; j < 2; ++j) {
                    accr[i][j] = __builtin_amdgcn_mfma_f32_16x16x32_f16(a, bfr[j], accr[i][j], 0, 0, 0);
                    acci[i][j] = __builtin_amdgcn_mfma_f32_16x16x32_f16(a, bfi[j], acci[i][j], 0, 0, 0);
                }
            }
        }
    }
    #pragma unroll
    for (int i = 0; i < 2; ++i)
        #pragma unroll
        for (int j = 0; j < 2; ++j) {
            int colc = col0 + wn + j * 16 + fm;
            float bbr = br[colc], bbi = bi[colc];
            if (omode == 2) {
                int rb = row0 + wm + i * 16 + fq * 4;
                int hq = rb >> 10, sq = rb & 1023;
                short4 o_r4 = make_short4(f2h(accr[i][j][0] + bbr), f2h(accr[i][j][1] + bbr),
                                          f2h(accr[i][j][2] + bbr), f2h(accr[i][j][3] + bbr));
                short4 o_i4 = make_short4(f2h(acci[i][j][0] + bbi), f2h(acci[i][j][1] + bbi),
                                          f2h(acci[i][j][2] + bbi), f2h(acci[i][j][3] + bbi));
                size_t ob = ((size_t)(hq * 128 + colc)) * 1024 + sq;
                *(short4*)&outr_[ob] = o_r4;
                *(short4*)&outi_[ob] = o_i4;
            } else {
                #pragma unroll
                for (int reg = 0; reg < 4; ++reg) {
                    int rr = row0 + wm + i * 16 + fq * 4 + reg;
                    float o_r = accr[i][j][reg] + bbr;
                    float o_i = acci[i][j][reg] + bbi;
                    if (per) {
                        o_r += per[(size_t)rr * 128 + (colc & 127)];
                        o_i += pei[(size_t)rr * 128 + (colc & 127)];
                    }
                    outr_[(size_t)rr * M + colc] = f2h(o_r);
                    outi_[(size_t)rr * M + colc] = f2h(o_i);
                }
            }
        }
}

// ============================================================
// o-projection: fp16 gated input gp, fp32 weights, fp32 out. 64x64 tiles.
// (unchanged — proven r1 kernel)
// ============================================================
__global__ __launch_bounds__(256) void oproj_mfma(
    const short* __restrict__ gp_r, const short* __restrict__ gp_i,
    const float* __restrict__ wr, const float* __restrict__ wi,
    const float* __restrict__ br, const float* __restrict__ bi,
    float* __restrict__ outr, float* __restrict__ outi)
{
    __shared__ short As[64 * 72], Brs[64 * 72], Bis[64 * 72];
    const int t = threadIdx.x;
    const int row0 = blockIdx.x * 64, col0 = blockIdx.y * 64;
    const int lane = t & 63, wid = t >> 6;
    const int wm = (wid >> 1) * 32, wn = (wid & 1) * 32;
    const int fm = lane & 15, fq = lane >> 4;
    f32x4 zero4 = {0.f, 0.f, 0.f, 0.f};
    f32x4 accr[2][2], acci[2][2];
    #pragma unroll
    for (int i = 0; i < 2; ++i)
        #pragma unroll
        for (int j = 0; j < 2; ++j) { accr[i][j] = zero4; acci[i][j] = zero4; }

    for (int c = 0; c < 4; ++c) {
        const bool hi = (c >= 2);
        const int kb = (c & 1) * 64;
        const short* Asrc = hi ? gp_i : gp_r;
        const float* Brsrc = hi ? wi : wr;
        const float* Bisrc = hi ? wr : wi;
        const float bsign = hi ? -1.0f : 1.0f;
        __syncthreads();
        #pragma unroll
        for (int it = 0; it < 4; ++it) {
            int lin = it * 256 + t;
            int r = lin >> 4, k4 = (lin & 15) * 4;
            *(short4*)&As[r * 72 + k4] = *(const short4*)&Asrc[(size_t)(row0 + r) * 128 + kb + k4];
            float4 vr = *(const float4*)&Brsrc[(size_t)(col0 + r) * 128 + kb + k4];
            *(short4*)&Brs[r * 72 + k4] = make_short4(f2h(bsign * vr.x), f2h(bsign * vr.y),
                                                      f2h(bsign * vr.z), f2h(bsign * vr.w));
            float4 vi = *(const float4*)&Bisrc[(size_t)(col0 + r) * 128 + kb + k4];
            *(short4*)&Bis[r * 72 + k4] = make_short4(f2h(vi.x), f2h(vi.y), f2h(vi.z), f2h(vi.w));
        }
        __syncthreads();
        #pragma unroll
        for (int ks = 0; ks < 64; ks += 32) {
            f16x8 bfr[2], bfi[2];
            #pragma unroll
            for (int j = 0; j < 2; ++j) {
                bfr[j] = *(const f16x8*)&Brs[(wn + j * 16 + fm) * 72 + ks + fq * 8];
                bfi[j] = *(const f16x8*)&Bis[(wn + j * 16 + fm) * 72 + ks + fq * 8];
            }
            #pragma unroll
            for (int i = 0; i < 2; ++i) {
                f16x8 a = *(const f16x8*)&As[(wm + i * 16 + fm) * 72 + ks + fq * 8];
                #pragma unroll
                for (int j = 0; j < 2; ++j) {
                    accr[i][j] = __builtin_amdgcn_mfma_f32_16x16x32_f16(a, bfr[j], accr[i][j], 0, 0, 0);
                    acci[i][j] = __builtin_amdgcn_mfma_f32_16x16x32_f16(a, bfi[j], acci[i][j], 0, 0, 0);
                }
            }
        }
    }
    #pragma unroll
    for (int i = 0; i < 2; ++i)
        #pragma unroll
        for (int j = 0; j < 2; ++j) {
            int colc = col0 + wn + j * 16 + fm;
            float bbr = br[colc], bbi = bi[colc];
            #pragma unroll
            for (int reg = 0; reg < 4; ++reg) {
                int rr = row0 + wm + i * 16 + fq * 4 + reg;
                outr[(size_t)rr * 128 + colc] = accr[i][j][reg] + bbr;
                outi[(size_t)rr * 128 + colc] = acci[i][j][reg] + bbi;
            }
        }
}

// ============================================================
// Scores (exact r1-proven): 64q x 128k tile, K-chunk 64, Q+Kt LDS-staged.
// ============================================================
__global__ __launch_bounds__(256) void score_mfma(
    const short* __restrict__ qp_r, const short* __restrict__ qp_i,
    const short* __restrict__ kp_r, const short* __restrict__ kp_i,
    short* __restrict__ w16, int h0)
{
    __shared__ short Qr[64 * 72], Qi[64 * 72], Kt[128 * 72];
    const int t = threadIdx.x;
    const int hh = blockIdx.z >> 1, map = blockIdx.z & 1;
    const int h = h0 + hh;
    const int q0 = blockIdx.x * 64, c0 = blockIdx.y * 128;
    const int lane = t & 63, wid = t >> 6;
    const int wm = (wid >> 1) * 32, wn = (wid & 1) * 64;
    const int fm = lane & 15, fq = lane >> 4;
    f32x4 zero4 = {0.f, 0.f, 0.f, 0.f};
    f32x4 sr[2][4], si[2][4];
    #pragma unroll
    for (int i = 0; i < 2; ++i)
        #pragma unroll
        for (int j = 0; j < 4; ++j) { sr[i][j] = zero4; si[i][j] = zero4; }

    for (int kb = 0; kb < 2; ++kb) {
        const int kbase = map * 128 + kb * 64;
        __syncthreads();
        #pragma unroll
        for (int i = 0; i < 4; ++i) {
            int lin = i * 256 + t;
            int r = lin >> 4, k4 = (lin & 15) * 4;
            size_t qb = (size_t)(h * S + q0 + r) * 256 + kbase + k4;
            *(short4*)&Qr[r * 72 + k4] = *(const short4*)&qp_r[qb];
            *(short4*)&Qi[r * 72 + k4] = *(const short4*)&qp_i[qb];
        }
        #pragma unroll
        for (int i = 0; i < 8; ++i) {
            int lin = i * 256 + t;
            int r = lin >> 4, k4 = (lin & 15) * 4;
            *(short4*)&Kt[r * 72 + k4] =
                *(const short4*)&kp_r[(size_t)(h * S + c0 + r) * 128 + kb * 64 + k4];
        }
        __syncthreads();
        f16x8 aR[2][2], aI[2][2]; // [ks][i]
        #pragma unroll
        for (int ks = 0; ks < 2; ++ks)
            #pragma unroll
            for (int i = 0; i < 2; ++i) {
                int ao = (wm + i * 16 + fm) * 72 + ks * 32 + fq * 8;
                aR[ks][i] = *(const f16x8*)&Qr[ao];
                aI[ks][i] = *(const f16x8*)&Qi[ao];
            }
        #pragma unroll
        for (int ks = 0; ks < 2; ++ks) {
            f16x8 b[4];
            #pragma unroll
            for (int j = 0; j < 4; ++j)
                b[j] = *(const f16x8*)&Kt[(wn + j * 16 + fm) * 72 + ks * 32 + fq * 8];
            #pragma unroll
            for (int i = 0; i < 2; ++i)
                #pragma unroll
                for (int j = 0; j < 4; ++j) {
                    sr[i][j] = __builtin_amdgcn_mfma_f32_16x16x32_f16(aR[ks][i], b[j], sr[i][j], 0, 0, 0);
                    si[i][j] = __builtin_amdgcn_mfma_f32_16x16x32_f16(aI[ks][i], b[j], si[i][j], 0, 0, 0);
                }
        }
        __syncthreads();
        #pragma unroll
        for (int i = 0; i < 8; ++i) {
            int lin = i * 256 + t;
            int r = lin >> 4, k4 = (lin & 15) * 4;
            *(short4*)&Kt[r * 72 + k4] =
                *(const short4*)&kp_i[(size_t)(h * S + c0 + r) * 128 + kb * 64 + k4];
        }
        __syncthreads();
        #pragma unroll
        for (int ks = 0; ks < 2; ++ks) {
            f16x8 b[4];
            #pragma unroll
            for (int j = 0; j < 4; ++j)
                b[j] = *(const f16x8*)&Kt[(wn + j * 16 + fm) * 72 + ks * 32 + fq * 8];
            f16x8 nR0 = fneg8(aR[ks][0]), nR1 = fneg8(aR[ks][1]);
            #pragma unroll
            for (int j = 0; j < 4; ++j) {
                sr[0][j] = __builtin_amdgcn_mfma_f32_16x16x32_f16(aI[ks][0], b[j], sr[0][j], 0, 0, 0);
                si[0][j] = __builtin_amdgcn_mfma_f32_16x16x32_f16(nR0, b[j], si[0][j], 0, 0, 0);
                sr[1][j] = __builtin_amdgcn_mfma_f32_16x16x32_f16(aI[ks][1], b[j], sr[1][j], 0, 0, 0);
                si[1][j] = __builtin_amdgcn_mfma_f32_16x16x32_f16(nR1, b[j], si[1][j], 0, 0, 0);
            }
        }
    }
    const float scale = 0.08838834764831845f;
    #pragma unroll
    for (int i = 0; i < 2; ++i)
        #pragma unroll
        for (int j = 0; j < 4; ++j) {
            int kcol = c0 + wn + j * 16 + fm;
            #pragma unroll
            for (int reg = 0; reg < 4; ++reg) {
                int q = q0 + wm + i * 16 + fq * 4 + reg;
                float r1 = sr[i][j][reg], I1 = si[i][j][reg];
                float m1 = sqrtf(fmaf(r1, r1, fmaf(I1, I1, 1e-8f))) * scale;
                w16[(((size_t)hh * 2 + map) * S + q) * S + kcol] = f2h(m1);
            }
        }
}

// ============================================================
// Per-row softmax STATS only (read-only over mags): stats[row]=(max, 1/sum).
// (exact r1-proven)
// ============================================================
__global__ __launch_bounds__(256) void smstats(const short* __restrict__ w16,
                                               float2* __restrict__ stats)
{
    const short* row = w16 + (size_t)blockIdx.x * S;
    int t = threadIdx.x;
    short4 s = ((const short4*)row)[t];
    float f0 = h2f(s.x), f1 = h2f(s.y), f2v = h2f(s.z), f3 = h2f(s.w);
    float m = fmaxf(fmaxf(f0, f1), fmaxf(f2v, f3));
    #pragma unroll
    for (int off = 32; off; off >>= 1) m = fmaxf(m, __shfl_xor(m, off));
    __shared__ float redm[4], reds[4];
    int w = t >> 6;
    if ((t & 63) == 0) redm[w] = m;
    __syncthreads();
    m = fmaxf(fmaxf(redm[0], redm[1]), fmaxf(redm[2], redm[3]));
    float ssum = __expf(f0 - m) + __expf(f1 - m) + __expf(f2v - m) + __expf(f3 - m);
    #pragma unroll
    for (int off = 32; off; off >>= 1) ssum += __shfl_xor(ssum, off);
    if ((t & 63) == 0) reds[w] = ssum;
    __syncthreads();
    if (t == 0) {
        float total = reds[0] + reds[1] + reds[2] + reds[3];
        stats[blockIdx.x] = make_float2(m, 1.0f / total);
    }
}

// ============================================================
// AV: 32q x full 128d, both maps, ONE complex comp per block (blockIdx.y).
// (exact r1-proven)
// ============================================================
__global__ __launch_bounds__(256) void av_mfma(
    const short* __restrict__ w16, const float2* __restrict__ stats,
    const short* __restrict__ vpT_r, const short* __restrict__ vpT_i,
    short* __restrict__ acat_r, short* __restrict__ acat_i, int h0)
{
    __shared__ short W1[32 * 72], W2[32 * 72], Vc[128 * 72];
    const int t = threadIdx.x;
    const int hh = blockIdx.z, h = h0 + hh;
    const int comp = blockIdx.y;
    const int q0 = blockIdx.x * 32;
    const short* vpT = comp ? vpT_i : vpT_r;
    short* acat = comp ? acat_i : acat_r;
    const float2* st1 = stats + ((size_t)hh * 2 + 0) * S;
    const float2* st2 = stats + ((size_t)hh * 2 + 1) * S;
    const int lane = t & 63, wid = t >> 6;
    const int wm = (wid >> 1) * 16, wn = (wid & 1) * 64;
    const int fm = lane & 15, fq = lane >> 4;
    f32x4 zero4 = {0.f, 0.f, 0.f, 0.f};
    f32x4 a1[4], a2[4];
    #pragma unroll
    for (int j = 0; j < 4; ++j) { a1[j] = zero4; a2[j] = zero4; }

    for (int k0 = 0; k0 < S; k0 += 64) {
        __syncthreads();
        #pragma unroll
        for (int it = 0; it < 2; ++it) {
            int lin = it * 256 + t;
            int r = lin >> 4, k4 = (lin & 15) * 4;
            float2 s1v = st1[q0 + r];
            float2 s2v = st2[q0 + r];
            short4 m1 = *(const short4*)&w16[(((size_t)hh * 2 + 0) * S + q0 + r) * S + k0 + k4];
            short4 m2 = *(const short4*)&w16[(((size_t)hh * 2 + 1) * S + q0 + r) * S + k0 + k4];
            *(short4*)&W1[r * 72 + k4] = make_short4(
                f2h(__expf(h2f(m1.x) - s1v.x) * s1v.y), f2h(__expf(h2f(m1.y) - s1v.x) * s1v.y),
                f2h(__expf(h2f(m1.z) - s1v.x) * s1v.y), f2h(__expf(h2f(m1.w) - s1v.x) * s1v.y));
            *(short4*)&W2[r * 72 + k4] = make_short4(
                f2h(__expf(h2f(m2.x) - s2v.x) * s2v.y), f2h(__expf(h2f(m2.y) - s2v.x) * s2v.y),
                f2h(__expf(h2f(m2.z) - s2v.x) * s2v.y), f2h(__expf(h2f(m2.w) - s2v.x) * s2v.y));
        }
        #pragma unroll
        for (int it = 0; it < 8; ++it) {
            int lin = it * 256 + t;
            int dd = lin >> 4, k4 = (lin & 15) * 4;
            *(short4*)&Vc[dd * 72 + k4] = *(const short4*)&vpT[(size_t)(h * 128 + dd) * 1024 + k0 + k4];
        }
        __syncthreads();
        #pragma unroll
        for (int ks = 0; ks < 64; ks += 32) {
            f16x8 b[4];
            #pragma unroll
            for (int j = 0; j < 4; ++j)
                b[j] = *(const f16x8*)&Vc[(wn + j * 16 + fm) * 72 + ks + fq * 8];
            int wo = (wm + fm) * 72 + ks + fq * 8;
            f16x8 w1f = *(const f16x8*)&W1[wo];
            f16x8 w2f = *(const f16x8*)&W2[wo];
            #pragma unroll
            for (int j = 0; j < 4; ++j) {
                a1[j] = __builtin_amdgcn_mfma_f32_16x16x32_f16(w1f, b[j], a1[j], 0, 0, 0);
                a2[j] = __builtin_amdgcn_mfma_f32_16x16x32_f16(w2f, b[j], a2[j], 0, 0, 0);
            }
        }
    }
    #pragma unroll
    for (int j = 0; j < 4; ++j) {
        int d = wn + j * 16 + fm;
        #pragma unroll
        for (int reg = 0; reg < 4; ++reg) {
            int q = q0 + wm + fq * 4 + reg;
            size_t rowb = (size_t)(h * S + q) * 256;
            acat[rowb + d]       = f2h(a1[j][reg]);
            acat[rowb + 128 + d] = f2h(a2[j][reg]);
        }
    }
}

// ============================================================
// RMS over 256 complex + sub_w + (a1 - lam*a2) + complex gate.
// (exact r1-proven)
// ============================================================
__global__ __launch_bounds__(256) void rmsgate_kernel(
    const short* __restrict__ acat_r, const short* __restrict__ acat_i,
    const float* __restrict__ sub_w, const float* __restrict__ lam_ptr,
    short* __restrict__ gp_r, short* __restrict__ gp_i)
{
    int row = blockIdx.x;
    int t = threadIdx.x;
    float ar = h2f(acat_r[(size_t)row * 256 + t]);
    float ai = h2f(acat_i[(size_t)row * 256 + t]);
    float ss = fmaf(ar, ar, ai * ai);
    #pragma unroll
    for (int off = 32; off; off >>= 1) ss += __shfl_xor(ss, off);
    __shared__ float red[4];
    if ((t & 63) == 0) red[t >> 6] = ss;
    __syncthreads();
    float total = red[0] + red[1] + red[2] + red[3];
    float inv_rms = 1.0f / sqrtf(total * (1.0f / 256.0f) + 1e-5f);
    float sw = sub_w[t];
    __shared__ float Cr[256], Ci[256];
    Cr[t] = ar * inv_rms * sw;
    Ci[t] = ai * inv_rms * sw;
    __syncthreads();
    if (t < 128) {
        float lam = lam_ptr[0];
        float o_r = Cr[t] - lam * Cr[t + 128];
        float o_i = Ci[t] - lam * Ci[t + 128];
        float gr = h2f(gp_r[(size_t)row * 128 + t]);
        float gi = h2f(gp_i[(size_t)row * 128 + t]);
        gp_r[(size_t)row * 128 + t] = f2h(gr * o_r - gi * o_i);
        gp_i[(size_t)row * 128 + t] = f2h(gr * o_i + gi * o_r);
    }
}

// ============================================================
extern "C" void kernel_launch(void* const* d_in, const int* in_sizes, int n_in,
                              void* d_out, int out_size, void* d_ws, size_t ws_size,
                              hipStream_t stream)
{
    (void)in_sizes; (void)n_in; (void)out_size;
    const float* q_r    = (const float*)d_in[0];
    const float* q_i    = (const float*)d_in[1];
    const float* k_r    = (const float*)d_in[2];
    const float* k_i    = (const float*)d_in[3];
    const float* v_r    = (const float*)d_in[4];
    const float* v_i    = (const float*)d_in[5];
    const float* pe_q_r = (const float*)d_in[6];
    const float* pe_q_i = (const float*)d_in[7];
    const float* pe_k_r = (const float*)d_in[8];
    const float* pe_k_i = (const float*)d_in[9];
    const float* qw_r   = (const float*)d_in[10];
    const float* qw_i   = (const float*)d_in[11];
    const float* qb_r   = (const float*)d_in[12];
    const float* qb_i   = (const float*)d_in[13];
    const float* kw_r   = (const float*)d_in[14];
    const float* kw_i   = (const float*)d_in[15];
    const float* kb_r   = (const float*)d_in[16];
    const float* kb_i   = (const float*)d_in[17];
    const float* vw_r   = (const float*)d_in[18];
    const float* vw_i   = (const float*)d_in[19];
    const float* vb_r   = (const float*)d_in[20];
    const float* vb_i   = (const float*)d_in[21];
    const float* gw_r   = (const float*)d_in[22];
    const float* gw_i   = (const float*)d_in[23];
    const float* gb_r   = (const float*)d_in[24];
    const float* gb_i   = (const float*)d_in[25];
    const float* ow_r   = (const float*)d_in[26];
    const float* ow_i   = (const float*)d_in[27];
    const float* ob_r   = (const float*)d_in[28];
    const float* ob_i   = (const float*)d_in[29];
    const float* lq1    = (const float*)d_in[30];
    const float* lk1    = (const float*)d_in[31];
    const float* lq2    = (const float*)d_in[32];
    const float* lk2    = (const float*)d_in[33];
    const float* sub_w  = (const float*)d_in[34];

    char* ws = (char*)d_ws;
    short* qp_r   = (short*)(ws + WS_QP_R);
    short* qp_i   = (short*)(ws + WS_QP_I);
    short* kp_r   = (short*)(ws + WS_KP_R);
    short* kp_i   = (short*)(ws + WS_KP_I);
    short* vpT_r  = (short*)(ws + WS_VPT_R);
    short* vpT_i  = (short*)(ws + WS_VPT_I);
    short* gp_r   = (short*)(ws + WS_GP_R);
    short* gp_i   = (short*)(ws + WS_GP_I);
    short* acat_r = (short*)(ws + WS_ACAT_R);
    short* acat_i = (short*)(ws + WS_ACAT_I);
    float* lam    = (float*)(ws + WS_LAM);
    short* w16    = (short*)(ws + WS_SC);
    // transient (pre-score) aliases inside the w16 region:
    short* xh = (short*)(ws + WS_SC);            // 6 fp16 input copies
    short* wh = (short*)(ws + WS_SC + WH_OFF_B); // 8 fp16 proj weights

    float* out_r = (float*)d_out;
    float* out_i = out_r + (size_t)NROWS * D;

    // head-chunking by workspace (depends only on ws_size -> graph-safe)
    size_t avail = ws_size > WS_SC ? ws_size - WS_SC : 0;
    int nh_chunk = (int)(avail / (W16_PER_HEAD + STAT_PER_HEAD));
    if (nh_chunk < 1) nh_chunk = 1;
    if (nh_chunk > H) nh_chunk = H;
    float2* stats = (float2*)(ws + WS_SC + (size_t)nh_chunk * W16_PER_HEAD);

    lam_kernel<<<1, 128, 0, stream>>>(lq1, lk1, lq2, lk2, lam);

    // pre-convert inputs + proj weights to fp16 (region dies when score writes w16)
    cvt_inputs<<<dim3(768, 6), 256, 0, stream>>>(q_r, q_i, k_r, k_i, v_r, v_i, xh);
    cvt_weights<<<dim3(16, 8), 256, 0, stream>>>(qw_r, qw_i, kw_r, kw_i,
                                                 vw_r, vw_i, gw_r, gw_i, wh);

    // ALL projections in one dispatch (fp16 sources -> pure-copy staging)
    proj_all<<<dim3(192, 10), 256, 0, stream>>>(
        xh, wh, pe_q_r, pe_q_i, pe_k_r, pe_k_i,
        qb_r, qb_i, kb_r, kb_i, vb_r, vb_i, gb_r, gb_i,
        qp_r, qp_i, kp_r, kp_i, vpT_r, vpT_i, gp_r, gp_i);

    for (int h0 = 0; h0 < H; h0 += nh_chunk) {
        int nhh = (H - h0 < nh_chunk) ? (H - h0) : nh_chunk;
        score_mfma<<<dim3(16, 8, nhh * 2), 256, 0, stream>>>(qp_r, qp_i, kp_r, kp_i, w16, h0);
        smstats<<<nhh * 2 * S, 256, 0, stream>>>(w16, stats);
        av_mfma<<<dim3(32, 2, nhh), 256, 0, stream>>>(w16, stats, vpT_r, vpT_i, acat_r, acat_i, h0);
    }

    rmsgate_kernel<<<NROWS, 256, 0, stream>>>(acat_r, acat_i, sub_w, lam, gp_r, gp_i);

    oproj_mfma<<<dim3(192, 2), 256, 0, stream>>>(gp_r, gp_i, ow_r, ow_i, ob_r, ob_i, out_r, out_i);
}

// Round 7
// 300.297 us; speedup vs baseline: 1.9157x; 1.0075x over previous
//
#include <hip/hip_runtime.h>
#include <math.h>

#define H 12
#define S 1024
#define D 128
#define NROWS (H * S) // 12288

typedef __attribute__((ext_vector_type(8))) _Float16 f16x8; // 8 fp16 in 4 VGPRs
typedef __attribute__((ext_vector_type(4))) float f32x4;
typedef __attribute__((ext_vector_type(4))) int i32x4;

__device__ __forceinline__ short f2h(float f) { // RNE float->fp16, bits as short
    _Float16 h = (_Float16)f;
    return __builtin_bit_cast(short, h);
}
__device__ __forceinline__ float h2f(short s) {
    return (float)__builtin_bit_cast(_Float16, s);
}
__device__ __forceinline__ f16x8 fneg8(f16x8 v) { // packed sign flip
    i32x4 u = __builtin_bit_cast(i32x4, v);
    u ^= (int)0x80008000;
    return __builtin_bit_cast(f16x8, u);
}

// ---- workspace layout (BYTE offsets) ----
// qp fp16 [12288][256] r/i ; kp fp16 [12288][128] r/i ; vpT fp16 [H][128][1024] r/i
// gp fp16 [12288][128] r/i ; acat fp16 [12288][256] r/i ;
// w16 fp16 per chunk-head 2*S*S ; stats float2 per chunk-head 2*S
#define WS_QP_R   0ULL
#define WS_QP_I   6291456ULL
#define WS_KP_R   12582912ULL
#define WS_KP_I   15728640ULL
#define WS_VPT_R  18874368ULL
#define WS_VPT_I  22020096ULL
#define WS_GP_R   25165824ULL
#define WS_GP_I   28311552ULL
#define WS_ACAT_R 31457280ULL
#define WS_ACAT_I 37748736ULL
#define WS_SC     44040448ULL
#define W16_PER_HEAD   4194304ULL // 2*1024*1024*2B
#define STAT_PER_HEAD  16384ULL   // 2*1024*8B

// ============================================================
// ALL FOUR projections in ONE dispatch. grid = (192, 10), 64x64 tiles.
// (exact r1-proven kernel)
// ============================================================
__global__ __launch_bounds__(256) void proj_all(
    const float* __restrict__ q_r, const float* __restrict__ q_i,
    const float* __restrict__ k_r, const float* __restrict__ k_i,
    const float* __restrict__ v_r, const float* __restrict__ v_i,
    const float* __restrict__ pe_q_r, const float* __restrict__ pe_q_i,
    const float* __restrict__ pe_k_r, const float* __restrict__ pe_k_i,
    const float* __restrict__ qw_r, const float* __restrict__ qw_i,
    const float* __restrict__ qb_r, const float* __restrict__ qb_i,
    const float* __restrict__ kw_r, const float* __restrict__ kw_i,
    const float* __restrict__ kb_r, const float* __restrict__ kb_i,
    const float* __restrict__ vw_r, const float* __restrict__ vw_i,
    const float* __restrict__ vb_r, const float* __restrict__ vb_i,
    const float* __restrict__ gw_r, const float* __restrict__ gw_i,
    const float* __restrict__ gb_r, const float* __restrict__ gb_i,
    short* __restrict__ qp_r, short* __restrict__ qp_i,
    short* __restrict__ kp_r, short* __restrict__ kp_i,
    short* __restrict__ vpT_r, short* __restrict__ vpT_i,
    short* __restrict__ gp_r, short* __restrict__ gp_i)
{
    const int y = blockIdx.y;
    const float *xr, *xi, *wr, *wi, *br, *bi, *per = nullptr, *pei = nullptr;
    short *outr_, *outi_;
    int M, omode, col0;
    if (y < 4)      { xr = q_r; xi = q_i; wr = qw_r; wi = qw_i; br = qb_r; bi = qb_i;
                      per = pe_q_r; pei = pe_q_i; outr_ = qp_r; outi_ = qp_i;
                      M = 256; omode = 1; col0 = y * 64; }
    else if (y < 6) { xr = k_r; xi = k_i; wr = kw_r; wi = kw_i; br = kb_r; bi = kb_i;
                      per = pe_k_r; pei = pe_k_i; outr_ = kp_r; outi_ = kp_i;
                      M = 128; omode = 1; col0 = (y - 4) * 64; }
    else if (y < 8) { xr = v_r; xi = v_i; wr = vw_r; wi = vw_i; br = vb_r; bi = vb_i;
                      outr_ = vpT_r; outi_ = vpT_i;
                      M = 128; omode = 2; col0 = (y - 6) * 64; }
    else            { xr = q_r; xi = q_i; wr = gw_r; wi = gw_i; br = gb_r; bi = gb_i;
                      outr_ = gp_r; outi_ = gp_i;
                      M = 128; omode = 1; col0 = (y - 8) * 64; }

    __shared__ short As[64 * 72], Brs[64 * 72], Bis[64 * 72];
    const int t = threadIdx.x;
    const int row0 = blockIdx.x * 64;
    const int lane = t & 63, wid = t >> 6;
    const int wm = (wid >> 1) * 32, wn = (wid & 1) * 32;
    const int fm = lane & 15, fq = lane >> 4;
    f32x4 zero4 = {0.f, 0.f, 0.f, 0.f};
    f32x4 accr[2][2], acci[2][2];
    #pragma unroll
    for (int i = 0; i < 2; ++i)
        #pragma unroll
        for (int j = 0; j < 2; ++j) { accr[i][j] = zero4; acci[i][j] = zero4; }

    for (int c = 0; c < 4; ++c) {
        const bool hi = (c >= 2);
        const int kb = (c & 1) * 64;
        const float* Asrc = hi ? xi : xr;
        const float* Brsrc = hi ? wi : wr;
        const float* Bisrc = hi ? wr : wi;
        const float bsign = hi ? -1.0f : 1.0f;
        __syncthreads();
        #pragma unroll
        for (int it = 0; it < 4; ++it) {
            int lin = it * 256 + t;
            int r = lin >> 4, k4 = (lin & 15) * 4;
            float4 va = *(const float4*)&Asrc[(size_t)(row0 + r) * 128 + kb + k4];
            *(short4*)&As[r * 72 + k4] = make_short4(f2h(va.x), f2h(va.y), f2h(va.z), f2h(va.w));
            float4 vr = *(const float4*)&Brsrc[(size_t)(col0 + r) * 128 + kb + k4];
            *(short4*)&Brs[r * 72 + k4] = make_short4(f2h(bsign * vr.x), f2h(bsign * vr.y),
                                                      f2h(bsign * vr.z), f2h(bsign * vr.w));
            float4 vi = *(const float4*)&Bisrc[(size_t)(col0 + r) * 128 + kb + k4];
            *(short4*)&Bis[r * 72 + k4] = make_short4(f2h(vi.x), f2h(vi.y), f2h(vi.z), f2h(vi.w));
        }
        __syncthreads();
        #pragma unroll
        for (int ks = 0; ks < 64; ks += 32) {
            f16x8 bfr[2], bfi[2];
            #pragma unroll
            for (int j = 0; j < 2; ++j) {
                bfr[j] = *(const f16x8*)&Brs[(wn + j * 16 + fm) * 72 + ks + fq * 8];
                bfi[j] = *(const f16x8*)&Bis[(wn + j * 16 + fm) * 72 + ks + fq * 8];
            }
            #pragma unroll
            for (int i = 0; i < 2; ++i) {
                f16x8 a = *(const f16x8*)&As[(wm + i * 16 + fm) * 72 + ks + fq * 8];
                #pragma unroll
                for (int j = 0; j < 2; ++j) {
                    accr[i][j] = __builtin_amdgcn_mfma_f32_16x16x32_f16(a, bfr[j], accr[i][j], 0, 0, 0);
                    acci[i][j] = __builtin_amdgcn_mfma_f32_16x16x32_f16(a, bfi[j], acci[i][j], 0, 0, 0);
                }
            }
        }
    }
    #pragma unroll
    for (int i = 0; i < 2; ++i)
        #pragma unroll
        for (int j = 0; j < 2; ++j) {
            int colc = col0 + wn + j * 16 + fm;
            float bbr = br[colc], bbi = bi[colc];
            if (omode == 2) {
                int rb = row0 + wm + i * 16 + fq * 4;
                int hq = rb >> 10, sq = rb & 1023;
                short4 o_r4 = make_short4(f2h(accr[i][j][0] + bbr), f2h(accr[i][j][1] + bbr),
                                          f2h(accr[i][j][2] + bbr), f2h(accr[i][j][3] + bbr));
                short4 o_i4 = make_short4(f2h(acci[i][j][0] + bbi), f2h(acci[i][j][1] + bbi),
                                          f2h(acci[i][j][2] + bbi), f2h(acci[i][j][3] + bbi));
                size_t ob = ((size_t)(hq * 128 + colc)) * 1024 + sq;
                *(short4*)&outr_[ob] = o_r4;
                *(short4*)&outi_[ob] = o_i4;
            } else {
                #pragma unroll
                for (int reg = 0; reg < 4; ++reg) {
                    int rr = row0 + wm + i * 16 + fq * 4 + reg;
                    float o_r = accr[i][j][reg] + bbr;
                    float o_i = acci[i][j][reg] + bbi;
                    if (per) {
                        o_r += per[(size_t)rr * 128 + (colc & 127)];
                        o_i += pei[(size_t)rr * 128 + (colc & 127)];
                    }
                    outr_[(size_t)rr * M + colc] = f2h(o_r);
                    outi_[(size_t)rr * M + colc] = f2h(o_i);
                }
            }
        }
}

// ============================================================
// o-projection, 32x64 tiles: grid (384, 2) = 768 blocks -> 3 blocks/CU
// (was 64-row tiles at 384 blocks = 1.5/CU, no latency hiding).
// Same fragment math as r1 with the i-loop removed.
// ============================================================
__global__ __launch_bounds__(256) void oproj_mfma(
    const short* __restrict__ gp_r, const short* __restrict__ gp_i,
    const float* __restrict__ wr, const float* __restrict__ wi,
    const float* __restrict__ br, const float* __restrict__ bi,
    float* __restrict__ outr, float* __restrict__ outi)
{
    __shared__ short As[32 * 72], Brs[64 * 72], Bis[64 * 72];
    const int t = threadIdx.x;
    const int row0 = blockIdx.x * 32, col0 = blockIdx.y * 64;
    const int lane = t & 63, wid = t >> 6;
    const int wm = (wid >> 1) * 16, wn = (wid & 1) * 32;
    const int fm = lane & 15, fq = lane >> 4;
    f32x4 zero4 = {0.f, 0.f, 0.f, 0.f};
    f32x4 accr[2], acci[2];
    #pragma unroll
    for (int j = 0; j < 2; ++j) { accr[j] = zero4; acci[j] = zero4; }

    for (int c = 0; c < 4; ++c) {
        const bool hi = (c >= 2);
        const int kb = (c & 1) * 64;
        const short* Asrc = hi ? gp_i : gp_r;
        const float* Brsrc = hi ? wi : wr;
        const float* Bisrc = hi ? wr : wi;
        const float bsign = hi ? -1.0f : 1.0f;
        __syncthreads();
        #pragma unroll
        for (int it = 0; it < 2; ++it) { // A: 32 rows x 64 cols
            int lin = it * 256 + t;
            int r = lin >> 4, k4 = (lin & 15) * 4;
            *(short4*)&As[r * 72 + k4] = *(const short4*)&Asrc[(size_t)(row0 + r) * 128 + kb + k4];
        }
        #pragma unroll
        for (int it = 0; it < 4; ++it) { // B: 64 rows x 64 cols
            int lin = it * 256 + t;
            int r = lin >> 4, k4 = (lin & 15) * 4;
            float4 vr = *(const float4*)&Brsrc[(size_t)(col0 + r) * 128 + kb + k4];
            *(short4*)&Brs[r * 72 + k4] = make_short4(f2h(bsign * vr.x), f2h(bsign * vr.y),
                                                      f2h(bsign * vr.z), f2h(bsign * vr.w));
            float4 vi = *(const float4*)&Bisrc[(size_t)(col0 + r) * 128 + kb + k4];
            *(short4*)&Bis[r * 72 + k4] = make_short4(f2h(vi.x), f2h(vi.y), f2h(vi.z), f2h(vi.w));
        }
        __syncthreads();
        #pragma unroll
        for (int ks = 0; ks < 64; ks += 32) {
            f16x8 bfr[2], bfi[2];
            #pragma unroll
            for (int j = 0; j < 2; ++j) {
                bfr[j] = *(const f16x8*)&Brs[(wn + j * 16 + fm) * 72 + ks + fq * 8];
                bfi[j] = *(const f16x8*)&Bis[(wn + j * 16 + fm) * 72 + ks + fq * 8];
            }
            f16x8 a = *(const f16x8*)&As[(wm + fm) * 72 + ks + fq * 8];
            #pragma unroll
            for (int j = 0; j < 2; ++j) {
                accr[j] = __builtin_amdgcn_mfma_f32_16x16x32_f16(a, bfr[j], accr[j], 0, 0, 0);
                acci[j] = __builtin_amdgcn_mfma_f32_16x16x32_f16(a, bfi[j], acci[j], 0, 0, 0);
            }
        }
    }
    #pragma unroll
    for (int j = 0; j < 2; ++j) {
        int colc = col0 + wn + j * 16 + fm;
        float bbr = br[colc], bbi = bi[colc];
        #pragma unroll
        for (int reg = 0; reg < 4; ++reg) {
            int rr = row0 + wm + fq * 4 + reg;
            outr[(size_t)rr * 128 + colc] = accr[j][reg] + bbr;
            outi[(size_t)rr * 128 + colc] = acci[j][reg] + bbi;
        }
    }
}

// ============================================================
// Scores (exact r1-proven): 64q x 128k tile, K-chunk 64, Q+Kt LDS-staged.
// ============================================================
__global__ __launch_bounds__(256) void score_mfma(
    const short* __restrict__ qp_r, const short* __restrict__ qp_i,
    const short* __restrict__ kp_r, const short* __restrict__ kp_i,
    short* __restrict__ w16, int h0)
{
    __shared__ short Qr[64 * 72], Qi[64 * 72], Kt[128 * 72];
    const int t = threadIdx.x;
    const int hh = blockIdx.z >> 1, map = blockIdx.z & 1;
    const int h = h0 + hh;
    const int q0 = blockIdx.x * 64, c0 = blockIdx.y * 128;
    const int lane = t & 63, wid = t >> 6;
    const int wm = (wid >> 1) * 32, wn = (wid & 1) * 64;
    const int fm = lane & 15, fq = lane >> 4;
    f32x4 zero4 = {0.f, 0.f, 0.f, 0.f};
    f32x4 sr[2][4], si[2][4];
    #pragma unroll
    for (int i = 0; i < 2; ++i)
        #pragma unroll
        for (int j = 0; j < 4; ++j) { sr[i][j] = zero4; si[i][j] = zero4; }

    for (int kb = 0; kb < 2; ++kb) {
        const int kbase = map * 128 + kb * 64;
        __syncthreads();
        #pragma unroll
        for (int i = 0; i < 4; ++i) {
            int lin = i * 256 + t;
            int r = lin >> 4, k4 = (lin & 15) * 4;
            size_t qb = (size_t)(h * S + q0 + r) * 256 + kbase + k4;
            *(short4*)&Qr[r * 72 + k4] = *(const short4*)&qp_r[qb];
            *(short4*)&Qi[r * 72 + k4] = *(const short4*)&qp_i[qb];
        }
        #pragma unroll
        for (int i = 0; i < 8; ++i) {
            int lin = i * 256 + t;
            int r = lin >> 4, k4 = (lin & 15) * 4;
            *(short4*)&Kt[r * 72 + k4] =
                *(const short4*)&kp_r[(size_t)(h * S + c0 + r) * 128 + kb * 64 + k4];
        }
        __syncthreads();
        f16x8 aR[2][2], aI[2][2]; // [ks][i]
        #pragma unroll
        for (int ks = 0; ks < 2; ++ks)
            #pragma unroll
            for (int i = 0; i < 2; ++i) {
                int ao = (wm + i * 16 + fm) * 72 + ks * 32 + fq * 8;
                aR[ks][i] = *(const f16x8*)&Qr[ao];
                aI[ks][i] = *(const f16x8*)&Qi[ao];
            }
        #pragma unroll
        for (int ks = 0; ks < 2; ++ks) {
            f16x8 b[4];
            #pragma unroll
            for (int j = 0; j < 4; ++j)
                b[j] = *(const f16x8*)&Kt[(wn + j * 16 + fm) * 72 + ks * 32 + fq * 8];
            #pragma unroll
            for (int i = 0; i < 2; ++i)
                #pragma unroll
                for (int j = 0; j < 4; ++j) {
                    sr[i][j] = __builtin_amdgcn_mfma_f32_16x16x32_f16(aR[ks][i], b[j], sr[i][j], 0, 0, 0);
                    si[i][j] = __builtin_amdgcn_mfma_f32_16x16x32_f16(aI[ks][i], b[j], si[i][j], 0, 0, 0);
                }
        }
        __syncthreads();
        #pragma unroll
        for (int i = 0; i < 8; ++i) {
            int lin = i * 256 + t;
            int r = lin >> 4, k4 = (lin & 15) * 4;
            *(short4*)&Kt[r * 72 + k4] =
                *(const short4*)&kp_i[(size_t)(h * S + c0 + r) * 128 + kb * 64 + k4];
        }
        __syncthreads();
        #pragma unroll
        for (int ks = 0; ks < 2; ++ks) {
            f16x8 b[4];
            #pragma unroll
            for (int j = 0; j < 4; ++j)
                b[j] = *(const f16x8*)&Kt[(wn + j * 16 + fm) * 72 + ks * 32 + fq * 8];
            f16x8 nR0 = fneg8(aR[ks][0]), nR1 = fneg8(aR[ks][1]);
            #pragma unroll
            for (int j = 0; j < 4; ++j) {
                sr[0][j] = __builtin_amdgcn_mfma_f32_16x16x32_f16(aI[ks][0], b[j], sr[0][j], 0, 0, 0);
                si[0][j] = __builtin_amdgcn_mfma_f32_16x16x32_f16(nR0, b[j], si[0][j], 0, 0, 0);
                sr[1][j] = __builtin_amdgcn_mfma_f32_16x16x32_f16(aI[ks][1], b[j], sr[1][j], 0, 0, 0);
                si[1][j] = __builtin_amdgcn_mfma_f32_16x16x32_f16(nR1, b[j], si[1][j], 0, 0, 0);
            }
        }
    }
    const float scale = 0.08838834764831845f;
    #pragma unroll
    for (int i = 0; i < 2; ++i)
        #pragma unroll
        for (int j = 0; j < 4; ++j) {
            int kcol = c0 + wn + j * 16 + fm;
            #pragma unroll
            for (int reg = 0; reg < 4; ++reg) {
                int q = q0 + wm + i * 16 + fq * 4 + reg;
                float r1 = sr[i][j][reg], I1 = si[i][j][reg];
                float m1 = sqrtf(fmaf(r1, r1, fmaf(I1, I1, 1e-8f))) * scale;
                w16[(((size_t)hh * 2 + map) * S + q) * S + kcol] = f2h(m1);
            }
        }
}

// ============================================================
// Per-row softmax STATS: now 2 rows/block, short8 loads (half the blocks).
// Row rl = t>>7 uses waves 2rl, 2rl+1.
// ============================================================
__global__ __launch_bounds__(256) void smstats(const short* __restrict__ w16,
                                               float2* __restrict__ stats)
{
    int t = threadIdx.x;
    int rl = t >> 7;                       // row within block (0/1)
    int row = blockIdx.x * 2 + rl;
    int li = t & 127;                      // lane within row
    const short* rp = w16 + (size_t)row * S;
    i32x4 v = *(const i32x4*)&rp[li * 8];
    short s8[8];
    *(i32x4*)s8 = v;
    float f[8];
    #pragma unroll
    for (int j = 0; j < 8; ++j) f[j] = h2f(s8[j]);
    float m = f[0];
    #pragma unroll
    for (int j = 1; j < 8; ++j) m = fmaxf(m, f[j]);
    #pragma unroll
    for (int off = 32; off; off >>= 1) m = fmaxf(m, __shfl_xor(m, off));
    __shared__ float redm[4], reds[4];
    int w = t >> 6; // wave 0..3
    if ((t & 63) == 0) redm[w] = m;
    __syncthreads();
    m = fmaxf(redm[rl * 2], redm[rl * 2 + 1]);
    float ssum = 0.f;
    #pragma unroll
    for (int j = 0; j < 8; ++j) ssum += __expf(f[j] - m);
    #pragma unroll
    for (int off = 32; off; off >>= 1) ssum += __shfl_xor(ssum, off);
    if ((t & 63) == 0) reds[w] = ssum;
    __syncthreads();
    if ((t & 127) == 0) {
        float total = reds[rl * 2] + reds[rl * 2 + 1];
        stats[row] = make_float2(m, 1.0f / total);
    }
}

// ============================================================
// AV: 32q x full 128d, both maps, ONE complex comp per block (blockIdx.y).
// (exact r1-proven)
// ============================================================
__global__ __launch_bounds__(256) void av_mfma(
    const short* __restrict__ w16, const float2* __restrict__ stats,
    const short* __restrict__ vpT_r, const short* __restrict__ vpT_i,
    short* __restrict__ acat_r, short* __restrict__ acat_i, int h0)
{
    __shared__ short W1[32 * 72], W2[32 * 72], Vc[128 * 72];
    const int t = threadIdx.x;
    const int hh = blockIdx.z, h = h0 + hh;
    const int comp = blockIdx.y;
    const int q0 = blockIdx.x * 32;
    const short* vpT = comp ? vpT_i : vpT_r;
    short* acat = comp ? acat_i : acat_r;
    const float2* st1 = stats + ((size_t)hh * 2 + 0) * S;
    const float2* st2 = stats + ((size_t)hh * 2 + 1) * S;
    const int lane = t & 63, wid = t >> 6;
    const int wm = (wid >> 1) * 16, wn = (wid & 1) * 64;
    const int fm = lane & 15, fq = lane >> 4;
    f32x4 zero4 = {0.f, 0.f, 0.f, 0.f};
    f32x4 a1[4], a2[4];
    #pragma unroll
    for (int j = 0; j < 4; ++j) { a1[j] = zero4; a2[j] = zero4; }

    for (int k0 = 0; k0 < S; k0 += 64) {
        __syncthreads();
        #pragma unroll
        for (int it = 0; it < 2; ++it) {
            int lin = it * 256 + t;
            int r = lin >> 4, k4 = (lin & 15) * 4;
            float2 s1v = st1[q0 + r];
            float2 s2v = st2[q0 + r];
            short4 m1 = *(const short4*)&w16[(((size_t)hh * 2 + 0) * S + q0 + r) * S + k0 + k4];
            short4 m2 = *(const short4*)&w16[(((size_t)hh * 2 + 1) * S + q0 + r) * S + k0 + k4];
            *(short4*)&W1[r * 72 + k4] = make_short4(
                f2h(__expf(h2f(m1.x) - s1v.x) * s1v.y), f2h(__expf(h2f(m1.y) - s1v.x) * s1v.y),
                f2h(__expf(h2f(m1.z) - s1v.x) * s1v.y), f2h(__expf(h2f(m1.w) - s1v.x) * s1v.y));
            *(short4*)&W2[r * 72 + k4] = make_short4(
                f2h(__expf(h2f(m2.x) - s2v.x) * s2v.y), f2h(__expf(h2f(m2.y) - s2v.x) * s2v.y),
                f2h(__expf(h2f(m2.z) - s2v.x) * s2v.y), f2h(__expf(h2f(m2.w) - s2v.x) * s2v.y));
        }
        #pragma unroll
        for (int it = 0; it < 8; ++it) {
            int lin = it * 256 + t;
            int dd = lin >> 4, k4 = (lin & 15) * 4;
            *(short4*)&Vc[dd * 72 + k4] = *(const short4*)&vpT[(size_t)(h * 128 + dd) * 1024 + k0 + k4];
        }
        __syncthreads();
        #pragma unroll
        for (int ks = 0; ks < 64; ks += 32) {
            f16x8 b[4];
            #pragma unroll
            for (int j = 0; j < 4; ++j)
                b[j] = *(const f16x8*)&Vc[(wn + j * 16 + fm) * 72 + ks + fq * 8];
            int wo = (wm + fm) * 72 + ks + fq * 8;
            f16x8 w1f = *(const f16x8*)&W1[wo];
            f16x8 w2f = *(const f16x8*)&W2[wo];
            #pragma unroll
            for (int j = 0; j < 4; ++j) {
                a1[j] = __builtin_amdgcn_mfma_f32_16x16x32_f16(w1f, b[j], a1[j], 0, 0, 0);
                a2[j] = __builtin_amdgcn_mfma_f32_16x16x32_f16(w2f, b[j], a2[j], 0, 0, 0);
            }
        }
    }
    #pragma unroll
    for (int j = 0; j < 4; ++j) {
        int d = wn + j * 16 + fm;
        #pragma unroll
        for (int reg = 0; reg < 4; ++reg) {
            int q = q0 + wm + fq * 4 + reg;
            size_t rowb = (size_t)(h * S + q) * 256;
            acat[rowb + d]       = f2h(a1[j][reg]);
            acat[rowb + 128 + d] = f2h(a2[j][reg]);
        }
    }
}

// ============================================================
// RMS + sub_w + (a1 - lam*a2) + complex gate. lam computed inline per
// block (2 tiny dots over 128 from L3 — cheaper than its own dispatch).
// ============================================================
__global__ __launch_bounds__(256) void rmsgate_kernel(
    const short* __restrict__ acat_r, const short* __restrict__ acat_i,
    const float* __restrict__ sub_w,
    const float* __restrict__ lq1, const float* __restrict__ lk1,
    const float* __restrict__ lq2, const float* __restrict__ lk2,
    short* __restrict__ gp_r, short* __restrict__ gp_i)
{
    int row = blockIdx.x;
    int t = threadIdx.x;
    float ar = h2f(acat_r[(size_t)row * 256 + t]);
    float ai = h2f(acat_i[(size_t)row * 256 + t]);
    float ss = fmaf(ar, ar, ai * ai);
    float p1 = (t < 128) ? lq1[t] * lk1[t] : 0.f;
    float p2 = (t < 128) ? lq2[t] * lk2[t] : 0.f;
    #pragma unroll
    for (int off = 32; off; off >>= 1) {
        ss += __shfl_xor(ss, off);
        p1 += __shfl_xor(p1, off);
        p2 += __shfl_xor(p2, off);
    }
    __shared__ float red[4], r1s[4], r2s[4];
    if ((t & 63) == 0) { red[t >> 6] = ss; r1s[t >> 6] = p1; r2s[t >> 6] = p2; }
    __syncthreads();
    float total = red[0] + red[1] + red[2] + red[3];
    float s1 = r1s[0] + r1s[1] + r1s[2] + r1s[3];
    float s2 = r2s[0] + r2s[1] + r2s[2] + r2s[3];
    float xlam = expf(s1) - expf(s2) + 0.3555090675909693f; // 0.8-0.6*exp(-0.3)
    float lam = 1.0f / (1.0f + expf(-xlam));
    float inv_rms = 1.0f / sqrtf(total * (1.0f / 256.0f) + 1e-5f);
    float sw = sub_w[t];
    __shared__ float Cr[256], Ci[256];
    Cr[t] = ar * inv_rms * sw;
    Ci[t] = ai * inv_rms * sw;
    __syncthreads();
    if (t < 128) {
        float o_r = Cr[t] - lam * Cr[t + 128];
        float o_i = Ci[t] - lam * Ci[t + 128];
        float gr = h2f(gp_r[(size_t)row * 128 + t]);
        float gi = h2f(gp_i[(size_t)row * 128 + t]);
        gp_r[(size_t)row * 128 + t] = f2h(gr * o_r - gi * o_i);
        gp_i[(size_t)row * 128 + t] = f2h(gr * o_i + gi * o_r);
    }
}

// ============================================================
extern "C" void kernel_launch(void* const* d_in, const int* in_sizes, int n_in,
                              void* d_out, int out_size, void* d_ws, size_t ws_size,
                              hipStream_t stream)
{
    (void)in_sizes; (void)n_in; (void)out_size;
    const float* q_r    = (const float*)d_in[0];
    const float* q_i    = (const float*)d_in[1];
    const float* k_r    = (const float*)d_in[2];
    const float* k_i    = (const float*)d_in[3];
    const float* v_r    = (const float*)d_in[4];
    const float* v_i    = (const float*)d_in[5];
    const float* pe_q_r = (const float*)d_in[6];
    const float* pe_q_i = (const float*)d_in[7];
    const float* pe_k_r = (const float*)d_in[8];
    const float* pe_k_i = (const float*)d_in[9];
    const float* qw_r   = (const float*)d_in[10];
    const float* qw_i   = (const float*)d_in[11];
    const float* qb_r   = (const float*)d_in[12];
    const float* qb_i   = (const float*)d_in[13];
    const float* kw_r   = (const float*)d_in[14];
    const float* kw_i   = (const float*)d_in[15];
    const float* kb_r   = (const float*)d_in[16];
    const float* kb_i   = (const float*)d_in[17];
    const float* vw_r   = (const float*)d_in[18];
    const float* vw_i   = (const float*)d_in[19];
    const float* vb_r   = (const float*)d_in[20];
    const float* vb_i   = (const float*)d_in[21];
    const float* gw_r   = (const float*)d_in[22];
    const float* gw_i   = (const float*)d_in[23];
    const float* gb_r   = (const float*)d_in[24];
    const float* gb_i   = (const float*)d_in[25];
    const float* ow_r   = (const float*)d_in[26];
    const float* ow_i   = (const float*)d_in[27];
    const float* ob_r   = (const float*)d_in[28];
    const float* ob_i   = (const float*)d_in[29];
    const float* lq1    = (const float*)d_in[30];
    const float* lk1    = (const float*)d_in[31];
    const float* lq2    = (const float*)d_in[32];
    const float* lk2    = (const float*)d_in[33];
    const float* sub_w  = (const float*)d_in[34];

    char* ws = (char*)d_ws;
    short* qp_r   = (short*)(ws + WS_QP_R);
    short* qp_i   = (short*)(ws + WS_QP_I);
    short* kp_r   = (short*)(ws + WS_KP_R);
    short* kp_i   = (short*)(ws + WS_KP_I);
    short* vpT_r  = (short*)(ws + WS_VPT_R);
    short* vpT_i  = (short*)(ws + WS_VPT_I);
    short* gp_r   = (short*)(ws + WS_GP_R);
    short* gp_i   = (short*)(ws + WS_GP_I);
    short* acat_r = (short*)(ws + WS_ACAT_R);
    short* acat_i = (short*)(ws + WS_ACAT_I);
    short* w16    = (short*)(ws + WS_SC);

    float* out_r = (float*)d_out;
    float* out_i = out_r + (size_t)NROWS * D;

    // head-chunking by workspace (depends only on ws_size -> graph-safe)
    size_t avail = ws_size > WS_SC ? ws_size - WS_SC : 0;
    int nh_chunk = (int)(avail / (W16_PER_HEAD + STAT_PER_HEAD));
    if (nh_chunk < 1) nh_chunk = 1;
    if (nh_chunk > H) nh_chunk = H;
    float2* stats = (float2*)(ws + WS_SC + (size_t)nh_chunk * W16_PER_HEAD);

    // ALL projections in one dispatch (q/k -> fp16 +PE; v -> fp16 T; g -> fp16)
    proj_all<<<dim3(192, 10), 256, 0, stream>>>(
        q_r, q_i, k_r, k_i, v_r, v_i, pe_q_r, pe_q_i, pe_k_r, pe_k_i,
        qw_r, qw_i, qb_r, qb_i, kw_r, kw_i, kb_r, kb_i,
        vw_r, vw_i, vb_r, vb_i, gw_r, gw_i, gb_r, gb_i,
        qp_r, qp_i, kp_r, kp_i, vpT_r, vpT_i, gp_r, gp_i);

    for (int h0 = 0; h0 < H; h0 += nh_chunk) {
        int nhh = (H - h0 < nh_chunk) ? (H - h0) : nh_chunk;
        score_mfma<<<dim3(16, 8, nhh * 2), 256, 0, stream>>>(qp_r, qp_i, kp_r, kp_i, w16, h0);
        smstats<<<nhh * S, 256, 0, stream>>>(w16, stats); // 2 rows/block
        av_mfma<<<dim3(32, 2, nhh), 256, 0, stream>>>(w16, stats, vpT_r, vpT_i, acat_r, acat_i, h0);
    }

    rmsgate_kernel<<<NROWS, 256, 0, stream>>>(acat_r, acat_i, sub_w,
                                              lq1, lk1, lq2, lk2, gp_r, gp_i);

    oproj_mfma<<<dim3(384, 2), 256, 0, stream>>>(gp_r, gp_i, ow_r, ow_i, ob_r, ob_i, out_r, out_i);
}